// Round 3
// baseline (214.727 us; speedup 1.0000x reference)
//
#include <hip/hip_runtime.h>
#include <math.h>

#define BB 8
#define NMODE 24

typedef __attribute__((ext_vector_type(8))) short bf16x8;
typedef __attribute__((ext_vector_type(4))) short bf16x4;
typedef __attribute__((ext_vector_type(4))) float f32x4;

#define MFMA32(a,b,c) __builtin_amdgcn_mfma_f32_16x16x32_bf16(a,b,c,0,0,0)

#if __has_builtin(__builtin_amdgcn_mfma_f32_16x16x16bf16_1k)
#define MFMA16(a,b,c) __builtin_amdgcn_mfma_f32_16x16x16bf16_1k(a,b,c,0,0,0)
#else
static __device__ __forceinline__ f32x4 MFMA16(bf16x4 a, bf16x4 b, f32x4 c){
    f32x4 d;
    asm("v_mfma_f32_16x16x16_bf16 %0, %1, %2, %3" : "=v"(d) : "v"(a), "v"(b), "v"(c));
    return d;
}
#endif

__device__ __forceinline__ short f2b(float f){
    unsigned u = __builtin_bit_cast(unsigned, f);
    u = (u + 0x7FFFu + ((u >> 16) & 1u)) >> 16;
    return (short)u;
}
__device__ __forceinline__ float gelu_f(float v) {
    float u = 0.7978845608028654f * (v + 0.044715f * v * v * v);
    float e = __expf(2.0f * u);
    float t = 1.0f - 2.0f / (e + 1.0f);
    return 0.5f * v * (1.0f + t);
}
__device__ __forceinline__ bf16x4 cvt4(f32x4 v){
    bf16x4 o;
    #pragma unroll
    for (int i=0;i<4;i++) o[i]=f2b(v[i]);
    return o;
}

// ======== kern0: precompute bf16 tables (weights^T, bias-augmented, DFT bases) ========
__global__ __launch_bounds__(256) void kern0(
    const float* __restrict__ Lw1, const float* __restrict__ Lb1, const float* __restrict__ Lw2,
    const float* __restrict__ Gw1, const float* __restrict__ Gb1, const float* __restrict__ Gw2,
    const float* __restrict__ uw,  const float* __restrict__ ubv,
    const float* __restrict__ Wuw, const float* __restrict__ Wub,
    const float* __restrict__ Huw, const float* __restrict__ Hub,
    const float* __restrict__ Msw, const float* __restrict__ Msb,
    const float* __restrict__ ow,
    short* __restrict__ G1a, short* __restrict__ L1a,
    short* __restrict__ G2T, short* __restrict__ L2T,
    short* __restrict__ WuCT, short* __restrict__ HuCT,
    short* __restrict__ owT, short* __restrict__ uwT, short* __restrict__ MsA,
    short* __restrict__ basisW, short* __restrict__ basis2P,
    float* __restrict__ dwu, float* __restrict__ dhu)
{
    const int bid = blockIdx.x, t = threadIdx.x;
    const float tp = 6.28318530717958648f/256.f;
    if (bid == 0){
        for (int idx=t; idx<1024; idx+=256){
            int o = idx>>5, c = idx&31;
            float s=0.f;
            for (int m=0;m<32;m++) s += uw[c*32+m]*Wuw[m*32+o];
            WuCT[o*32+c] = f2b(s);
        }
        if (t<32){ float s=Wub[t]; for (int m=0;m<32;m++) s += ubv[m]*Wuw[m*32+t]; dwu[t]=s; }
    } else if (bid == 1){
        for (int idx=t; idx<1024; idx+=256){
            int o = idx>>5, c = idx&31;
            float s=0.f;
            for (int m=0;m<32;m++) s += uw[c*32+m]*Huw[m*32+o];
            HuCT[o*32+c] = f2b(s);
        }
        if (t<32){ float s=Hub[t]; for (int m=0;m<32;m++) s += ubv[m]*Huw[m*32+t]; dhu[t]=s; }
    } else if (bid == 2){
        for (int idx=t; idx<1024; idx+=256){
            int hd = idx>>4, k2 = idx&15;
            G1a[idx] = f2b(k2<4 ? Gw1[k2*64+hd] : (k2==4 ? Gb1[hd] : 0.f));
            L1a[idx] = f2b(k2<4 ? Lw1[k2*64+hd] : (k2==4 ? Lb1[hd] : 0.f));
        }
    } else if (bid == 3){
        for (int idx=t; idx<2048; idx+=256){ int o=idx>>6, m=idx&63; G2T[idx]=f2b(Gw2[m*32+o]); }
    } else if (bid == 4){
        for (int idx=t; idx<2048; idx+=256){ int o=idx>>6, m=idx&63; L2T[idx]=f2b(Lw2[m*32+o]); }
    } else if (bid == 5){
        for (int idx=t; idx<1024; idx+=256){
            int o=idx>>5, c=idx&31;
            owT[idx]=f2b(ow[c*32+o]);
            uwT[idx]=f2b(uw[c*32+o]);
        }
    } else if (bid == 6){
        for (int idx=t; idx<512; idx+=256){
            int o=idx>>4, k2=idx&15;
            MsA[idx]=f2b(k2<4 ? Msw[k2*32+o] : (k2==4 ? Msb[o] : 0.f));
        }
    } else if (bid < 15){
        int base=(bid-7)*1024;
        for (int i=t; i<1024; i+=256){
            int idx=base+i; int m=idx>>8, w=idx&255;
            float v=0.f;
            if (m<12)       v = cosf(tp*(float)((m*w)&255));
            else if (m<24)  v = sinf(tp*(float)(((m-12)*w)&255));
            basisW[idx]=f2b(v);
        }
    } else if (bid < 23){
        int base=(bid-15)*1024;
        for (int i=t; i<1024; i+=256){
            int idx=base+i; int w=idx>>5, k=idx&31;
            float v=0.f;
            if (k<24){ int m=k>>1; float a=tp*(float)((m*w)&255); v=(k&1)? -sinf(a):cosf(a); }
            basis2P[idx]=f2b(v);
        }
    }
}

// ======== kernA: transposed chain v^T = (L^T)*(u^T)+Ms^T, then w-DFT (MFMA K=32) ========
__global__ __launch_bounds__(256) void kernA(
    const float* __restrict__ x, const float* __restrict__ kk,
    const float* __restrict__ Lb2, const float* __restrict__ ubv,
    const short* __restrict__ L1a, const short* __restrict__ L2T,
    const short* __restrict__ uwT, const short* __restrict__ MsA,
    const short* __restrict__ basisW, float* __restrict__ A1)
{
    __shared__ short vT[32*264];   // [ch][pixel] padded
    const int bh = blockIdx.x, b = bh>>8, h = bh&255;
    const int tid = threadIdx.x, l = tid&63, wv = tid>>6;
    const int q = l>>4, r = l&15;
    const f32x4 z4 = {0.f,0.f,0.f,0.f};

    // B-fragments: k (bias-augmented at k=4) and x
    bf16x4 kB[4], xB[4][2];
    #pragma unroll
    for (int nt=0; nt<4; nt++){
        int p = wv*64 + nt*16 + r;
        bf16x4 tkn = {0,0,0,0};
        if (q==0){
            float4 k4 = *(const float4*)(kk + ((size_t)bh*256+p)*4);
            tkn[0]=f2b(k4.x); tkn[1]=f2b(k4.y); tkn[2]=f2b(k4.z); tkn[3]=f2b(k4.w);
        } else if (q==1){ tkn[0] = (short)0x3F80; }  // bf16 1.0 -> bias channel
        kB[nt]=tkn;
        #pragma unroll
        for (int ks=0; ks<2; ks++){
            float4 x4 = *(const float4*)(x + ((size_t)bh*256+p)*32 + 16*ks + 4*q);
            bf16x4 u; u[0]=f2b(x4.x); u[1]=f2b(x4.y); u[2]=f2b(x4.z); u[3]=f2b(x4.w);
            xB[nt][ks]=u;
        }
    }

    // hidden = gelu(k@Lw1 + Lb1)  (bias folded), kept as B-fragments
    bf16x4 hidB[4][4];
    #pragma unroll
    for (int mt=0; mt<4; mt++){
        bf16x4 la = *(const bf16x4*)(L1a + (r+16*mt)*16 + 4*q);
        #pragma unroll
        for (int nt=0; nt<4; nt++){
            f32x4 acc = MFMA16(la, kB[nt], z4);
            f32x4 g;
            #pragma unroll
            for (int i=0;i<4;i++) g[i]=gelu_f(acc[i]);
            hidB[mt][nt] = cvt4(g);
        }
    }

    // L^T, u^T, Ms^T -> v^T -> LDS
    #pragma unroll
    for (int mt=0; mt<2; mt++){
        bf16x4 ma  = *(const bf16x4*)(MsA + (r+16*mt)*16 + 4*q);
        bf16x4 ua0 = *(const bf16x4*)(uwT + (r+16*mt)*32 + 4*q);
        bf16x4 ua1 = *(const bf16x4*)(uwT + (r+16*mt)*32 + 16 + 4*q);
        bf16x4 l2f[4];
        #pragma unroll
        for (int ks=0; ks<4; ks++)
            l2f[ks] = *(const bf16x4*)(L2T + (r+16*mt)*64 + 16*ks + 4*q);
        #pragma unroll
        for (int nt=0; nt<4; nt++){
            f32x4 aU = MFMA16(ua0, xB[nt][0], z4);
            aU = MFMA16(ua1, xB[nt][1], aU);
            f32x4 aM = MFMA16(ma, kB[nt], z4);
            f32x4 aL = z4;
            #pragma unroll
            for (int ks=0; ks<4; ks++) aL = MFMA16(l2f[ks], hidB[ks][nt], aL);
            #pragma unroll
            for (int rg=0; rg<4; rg++){
                int ch = 16*mt + 4*q + rg;
                float v = (aL[rg] + Lb2[ch]) * (aU[rg] + ubv[ch]) + aM[rg];
                vT[ch*264 + wv*64 + nt*16 + r] = f2b(v);
            }
        }
    }
    __syncthreads();

    // w-DFT: C[mode][ch] = sum_w basisW[mode][w] * v^T[ch][w]
    const int mt2 = wv>>1, nt2 = wv&1;
    f32x4 accD = z4;
    #pragma unroll
    for (int ks=0; ks<8; ks++){
        bf16x8 av = *(const bf16x8*)(basisW + (r+16*mt2)*256 + 32*ks + 8*q);
        bf16x8 bv = *(const bf16x8*)(vT + (r+16*nt2)*264 + 32*ks + 8*q);
        accD = MFMA32(av, bv, accD);
    }
    #pragma unroll
    for (int rg=0; rg<4; rg++){
        int mode = 16*mt2 + 4*q + rg;
        int ch = r + 16*nt2;
        if (mode < 12)
            A1[((size_t)(b*12+mode)*256 + h)*64 + ch*2] = accD[rg];
        else if (mode < 24)
            A1[((size_t)(b*12+mode-12)*256 + h)*64 + ch*2 + 1] = -accD[rg];
    }
}

// ======== kernC: h-DFT, spectral multiply, inverse h-DFT; writes bf16 Tp[bh][o][2j] ========
__global__ __launch_bounds__(256) void kernC(
    const float* __restrict__ A1,
    const float* __restrict__ k1r, const float* __restrict__ k1i,
    const float* __restrict__ k2r, const float* __restrict__ k2i,
    short* __restrict__ Tp)
{
    __shared__ float vft[NMODE * 64];
    __shared__ float Sm[NMODE * 64];
    __shared__ float ct[256], st[256];

    const int b = blockIdx.x / 12;
    const int j = blockIdx.x % 12;
    const int t = threadIdx.x;

    __sincosf(0.0245436926066f * (float)t, &st[t], &ct[t]);
    __syncthreads();

    const float* ag = A1 + (size_t)(b*12 + j) * 16384;
    const int c  = t & 31;
    const int i0 = t >> 5;

    {
        const int ia0 = i0;
        const int ia1 = (i0 + 8 < 12) ? (i0 + 8) : (232 + i0 + 8);
        const int ia2 = 232 + i0 + 16;
        float r0=0,m0=0, r1=0,m1=0, r2=0,m2=0;
        #pragma unroll 4
        for (int hh = 0; hh < 256; hh++) {
            float2 av = *reinterpret_cast<const float2*>(ag + hh*64 + c*2);
            int p0 = (ia0*hh) & 255; float c0 = ct[p0], s0 = st[p0];
            int p1 = (ia1*hh) & 255; float c1 = ct[p1], s1 = st[p1];
            int p2 = (ia2*hh) & 255; float c2 = ct[p2], s2 = st[p2];
            r0 += av.x*c0 + av.y*s0;  m0 += av.y*c0 - av.x*s0;
            r1 += av.x*c1 + av.y*s1;  m1 += av.y*c1 - av.x*s1;
            r2 += av.x*c2 + av.y*s2;  m2 += av.y*c2 - av.x*s2;
        }
        vft[(i0      *32 + c)*2] = r0; vft[(i0      *32 + c)*2 + 1] = m0;
        vft[((i0+8 ) *32 + c)*2] = r1; vft[((i0+8 ) *32 + c)*2 + 1] = m1;
        vft[((i0+16) *32 + c)*2] = r2; vft[((i0+16) *32 + c)*2 + 1] = m2;
    }
    __syncthreads();

    {
        const int o = t & 31;
        const float* wr0 = k1r;                  const float* wi0 = k1i;                  const int ii0 = i0;
        const float* wr1 = (i0+8 < 12) ? k1r : k2r;
        const float* wi1 = (i0+8 < 12) ? k1i : k2i;
        const int    ii1 = (i0+8 < 12) ? (i0+8) : (i0-4);
        const float* wr2 = k2r;                  const float* wi2 = k2i;                  const int ii2 = i0 + 4;
        float r0=0,m0=0, r1=0,m1=0, r2=0,m2=0;
        #pragma unroll
        for (int cc = 0; cc < 32; cc++) {
            float vr0 = vft[(i0      *32 + cc)*2], vi0 = vft[(i0      *32 + cc)*2 + 1];
            float vr1 = vft[((i0+8 ) *32 + cc)*2], vi1 = vft[((i0+8 ) *32 + cc)*2 + 1];
            float vr2 = vft[((i0+16) *32 + cc)*2], vi2 = vft[((i0+16) *32 + cc)*2 + 1];
            size_t base = (size_t)(cc*32 + o) * 144 + j;
            float kr0 = wr0[base + (size_t)ii0*12], ki0 = wi0[base + (size_t)ii0*12];
            float kr1 = wr1[base + (size_t)ii1*12], ki1 = wi1[base + (size_t)ii1*12];
            float kr2 = wr2[base + (size_t)ii2*12], ki2 = wi2[base + (size_t)ii2*12];
            r0 += vr0*kr0 - vi0*ki0;  m0 += vr0*ki0 + vi0*kr0;
            r1 += vr1*kr1 - vi1*ki1;  m1 += vr1*ki1 + vi1*kr1;
            r2 += vr2*kr2 - vi2*ki2;  m2 += vr2*ki2 + vi2*kr2;
        }
        Sm[(i0      *32 + o)*2] = r0; Sm[(i0      *32 + o)*2 + 1] = m0;
        Sm[((i0+8 ) *32 + o)*2] = r1; Sm[((i0+8 ) *32 + o)*2 + 1] = m1;
        Sm[((i0+16) *32 + o)*2] = r2; Sm[((i0+16) *32 + o)*2 + 1] = m2;
    }
    __syncthreads();

    {
        float Tre[32], Tim[32];
        #pragma unroll
        for (int o = 0; o < 32; o++) { Tre[o] = 0.f; Tim[o] = 0.f; }
        #pragma unroll 4
        for (int m = 0; m < 24; m++) {
            int iam = (m < 12) ? m : (232 + m);
            int ph = (iam * t) & 255;
            float cc2 = ct[ph], ss2 = st[ph];
            #pragma unroll
            for (int o = 0; o < 32; o++) {
                float sr = Sm[(m*32 + o)*2], si = Sm[(m*32 + o)*2 + 1];
                Tre[o] += sr*cc2 - si*ss2;
                Tim[o] += sr*ss2 + si*cc2;
            }
        }
        const float sc = (j == 0) ? (1.0f/65536.0f) : (2.0f/65536.0f);
        short* dst = Tp + ((size_t)(b*256 + t))*1024;   // [o][32]
        #pragma unroll
        for (int o = 0; o < 32; o++) {
            dst[o*32 + 2*j]     = f2b(Tre[o] * sc);
            dst[o*32 + 2*j + 1] = f2b(Tim[o] * sc);
        }
        if (j == 0){
            #pragma unroll
            for (int o = 0; o < 32; o++)
                #pragma unroll
                for (int kp = 24; kp < 32; kp++) dst[o*32 + kp] = 0;
        }
    }
}

// ======== kernD: fully in-register transposed chain; zero LDS, zero barriers ========
__global__ __launch_bounds__(256) void kernD(
    const float* __restrict__ x, const float* __restrict__ kk,
    const float* __restrict__ Gb2, const float* __restrict__ obv,
    const short* __restrict__ G1a, const short* __restrict__ G2T,
    const short* __restrict__ WuCT, const short* __restrict__ HuCT,
    const short* __restrict__ owT, const short* __restrict__ basis2P,
    const short* __restrict__ Tp,
    const float* __restrict__ dwu, const float* __restrict__ dhu,
    float* __restrict__ out)
{
    const int bh = blockIdx.x;
    const int tid = threadIdx.x, l = tid&63, wv = tid>>6;
    const int q = l>>4, r = l&15;
    const f32x4 z4 = {0.f,0.f,0.f,0.f};

    bf16x4 kB[4], xB[4][2];
    #pragma unroll
    for (int nt=0; nt<4; nt++){
        int p = wv*64 + nt*16 + r;
        bf16x4 tkn = {0,0,0,0};
        if (q==0){
            float4 k4 = *(const float4*)(kk + ((size_t)bh*256+p)*4);
            tkn[0]=f2b(k4.x); tkn[1]=f2b(k4.y); tkn[2]=f2b(k4.z); tkn[3]=f2b(k4.w);
        } else if (q==1){ tkn[0] = (short)0x3F80; }
        kB[nt]=tkn;
        #pragma unroll
        for (int ks=0; ks<2; ks++){
            float4 x4 = *(const float4*)(x + ((size_t)bh*256+p)*32 + 16*ks + 4*q);
            bf16x4 u; u[0]=f2b(x4.x); u[1]=f2b(x4.y); u[2]=f2b(x4.z); u[3]=f2b(x4.w);
            xB[nt][ks]=u;
        }
    }

    // hidden = gelu(k@Gw1 + Gb1) as B-fragments
    bf16x4 hidB[4][4];
    #pragma unroll
    for (int mt=0; mt<4; mt++){
        bf16x4 ga = *(const bf16x4*)(G1a + (r+16*mt)*16 + 4*q);
        #pragma unroll
        for (int nt=0; nt<4; nt++){
            f32x4 acc = MFMA16(ga, kB[nt], z4);
            f32x4 g;
            #pragma unroll
            for (int i=0;i<4;i++) g[i]=gelu_f(acc[i]);
            hidB[mt][nt] = cvt4(g);
        }
    }

    // Fv^T = Tp(bh) @ basis2P^T
    f32x4 aF[2][4];
    {
        bf16x4 bb[4][2];
        #pragma unroll
        for (int nt=0; nt<4; nt++){
            int p = wv*64 + nt*16 + r;
            bb[nt][0] = *(const bf16x4*)(basis2P + p*32 + 4*q);
            bb[nt][1] = *(const bf16x4*)(basis2P + p*32 + 16 + 4*q);
        }
        #pragma unroll
        for (int mt=0; mt<2; mt++){
            bf16x4 t0 = *(const bf16x4*)(Tp + (size_t)bh*1024 + (r+16*mt)*32 + 4*q);
            bf16x4 t1 = *(const bf16x4*)(Tp + (size_t)bh*1024 + (r+16*mt)*32 + 16 + 4*q);
            #pragma unroll
            for (int nt=0; nt<4; nt++){
                f32x4 acc = MFMA16(t0, bb[nt][0], z4);
                aF[mt][nt] = MFMA16(t1, bb[nt][1], acc);
            }
        }
    }

    // aF := (Hu + dhu) - Fv
    #pragma unroll
    for (int mt=0; mt<2; mt++){
        bf16x4 h0 = *(const bf16x4*)(HuCT + (r+16*mt)*32 + 4*q);
        bf16x4 h1 = *(const bf16x4*)(HuCT + (r+16*mt)*32 + 16 + 4*q);
        #pragma unroll
        for (int nt=0; nt<4; nt++){
            f32x4 aHu = MFMA16(h0, xB[nt][0], z4);
            aHu = MFMA16(h1, xB[nt][1], aHu);
            #pragma unroll
            for (int rg=0; rg<4; rg++){
                int ch = 16*mt + 4*q + rg;
                aF[mt][nt][rg] = (aHu[rg] + dhu[ch]) - aF[mt][nt][rg];
            }
        }
    }

    // aF := (G + Gb2) * aF
    #pragma unroll
    for (int mt=0; mt<2; mt++){
        bf16x4 g2[4];
        #pragma unroll
        for (int ks=0; ks<4; ks++)
            g2[ks] = *(const bf16x4*)(G2T + (r+16*mt)*64 + 16*ks + 4*q);
        #pragma unroll
        for (int nt=0; nt<4; nt++){
            f32x4 aG = z4;
            #pragma unroll
            for (int ks=0; ks<4; ks++) aG = MFMA16(g2[ks], hidB[ks][nt], aG);
            #pragma unroll
            for (int rg=0; rg<4; rg++){
                int ch = 16*mt + 4*q + rg;
                aF[mt][nt][rg] = (aG[rg] + Gb2[ch]) * aF[mt][nt][rg];
            }
        }
    }

    // born = (Wu + dwu) - aF  -> B-fragments
    bf16x4 bornB[2][4];
    #pragma unroll
    for (int mt=0; mt<2; mt++){
        bf16x4 w0 = *(const bf16x4*)(WuCT + (r+16*mt)*32 + 4*q);
        bf16x4 w1 = *(const bf16x4*)(WuCT + (r+16*mt)*32 + 16 + 4*q);
        #pragma unroll
        for (int nt=0; nt<4; nt++){
            f32x4 aW = MFMA16(w0, xB[nt][0], z4);
            aW = MFMA16(w1, xB[nt][1], aW);
            f32x4 brn;
            #pragma unroll
            for (int rg=0; rg<4; rg++){
                int ch = 16*mt + 4*q + rg;
                brn[rg] = (aW[rg] + dwu[ch]) - aF[mt][nt][rg];
            }
            bornB[mt][nt] = cvt4(brn);
        }
    }

    // out = gelu(born @ ow + ob), stored transposed-exact (4 consecutive ch per lane)
    #pragma unroll
    for (int mt=0; mt<2; mt++){
        bf16x4 o0 = *(const bf16x4*)(owT + (r+16*mt)*32 + 4*q);
        bf16x4 o1 = *(const bf16x4*)(owT + (r+16*mt)*32 + 16 + 4*q);
        #pragma unroll
        for (int nt=0; nt<4; nt++){
            f32x4 aO = MFMA16(o0, bornB[0][nt], z4);
            aO = MFMA16(o1, bornB[1][nt], aO);
            float4 res;
            res.x = gelu_f(aO[0] + obv[16*mt + 4*q + 0]);
            res.y = gelu_f(aO[1] + obv[16*mt + 4*q + 1]);
            res.z = gelu_f(aO[2] + obv[16*mt + 4*q + 2]);
            res.w = gelu_f(aO[3] + obv[16*mt + 4*q + 3]);
            *(float4*)(out + ((size_t)bh*256 + wv*64 + nt*16 + r)*32 + 16*mt + 4*q) = res;
        }
    }
}

extern "C" void kernel_launch(void* const* d_in, const int* in_sizes, int n_in,
                              void* d_out, int out_size, void* d_ws, size_t ws_size,
                              hipStream_t stream)
{
    const float* x   = (const float*)d_in[0];
    const float* kk  = (const float*)d_in[1];
    const float* Lw1 = (const float*)d_in[2];
    const float* Lb1 = (const float*)d_in[3];
    const float* Lw2 = (const float*)d_in[4];
    const float* Lb2 = (const float*)d_in[5];
    const float* Gw1 = (const float*)d_in[6];
    const float* Gb1 = (const float*)d_in[7];
    const float* Gw2 = (const float*)d_in[8];
    const float* Gb2 = (const float*)d_in[9];
    const float* uw  = (const float*)d_in[10];
    const float* ub  = (const float*)d_in[11];
    const float* Wuw = (const float*)d_in[12];
    const float* Wub = (const float*)d_in[13];
    const float* Huw = (const float*)d_in[14];
    const float* Hub = (const float*)d_in[15];
    const float* Msw = (const float*)d_in[16];
    const float* Msb = (const float*)d_in[17];
    const float* ow  = (const float*)d_in[18];
    const float* ob  = (const float*)d_in[19];
    const float* k1r = (const float*)d_in[20];
    const float* k1i = (const float*)d_in[21];
    const float* k2r = (const float*)d_in[22];
    const float* k2i = (const float*)d_in[23];

    float* A1 = (float*)d_ws;                 // 1,572,864 floats (6 MB)
    short* Tp = (short*)(A1 + 1572864);       // 2,097,152 shorts (4 MB)
    short* tab = Tp + 2097152;
    short* G1a  = tab;              // 1024
    short* L1a  = G1a + 1024;       // 1024
    short* G2T  = L1a + 1024;       // 2048
    short* L2T  = G2T + 2048;       // 2048
    short* WuCT = L2T + 2048;       // 1024
    short* HuCT = WuCT + 1024;      // 1024
    short* owT  = HuCT + 1024;      // 1024
    short* uwT  = owT + 1024;       // 1024
    short* MsA  = uwT + 1024;       // 512
    short* basisW  = MsA + 512;     // 8192
    short* basis2P = basisW + 8192; // 8192
    float* dwu = (float*)(basis2P + 8192);
    float* dhu = dwu + 32;

    float* outp = (float*)d_out;

    kern0<<<23, 256, 0, stream>>>(Lw1, Lb1, Lw2, Gw1, Gb1, Gw2, uw, ub,
                                  Wuw, Wub, Huw, Hub, Msw, Msb, ow,
                                  G1a, L1a, G2T, L2T, WuCT, HuCT, owT, uwT, MsA,
                                  basisW, basis2P, dwu, dhu);
    kernA<<<BB*256, 256, 0, stream>>>(x, kk, Lb2, ub, L1a, L2T, uwT, MsA, basisW, A1);
    kernC<<<BB*12, 256, 0, stream>>>(A1, k1r, k1i, k2r, k2i, Tp);
    kernD<<<BB*256, 256, 0, stream>>>(x, kk, Gb2, ob, G1a, G2T, WuCT, HuCT, owT,
                                      basis2P, Tp, dwu, dhu, outp);
}

// Round 5
// 197.806 us; speedup vs baseline: 1.0855x; 1.0855x over previous
//
#include <hip/hip_runtime.h>
#include <math.h>

#define BB 8
#define NMODE 24

typedef __attribute__((ext_vector_type(8))) short bf16x8;
typedef __attribute__((ext_vector_type(4))) short bf16x4;
typedef __attribute__((ext_vector_type(4))) float f32x4;

#define MFMA32(a,b,c) __builtin_amdgcn_mfma_f32_16x16x32_bf16(a,b,c,0,0,0)

#if __has_builtin(__builtin_amdgcn_mfma_f32_16x16x16bf16_1k)
#define MFMA16(a,b,c) __builtin_amdgcn_mfma_f32_16x16x16bf16_1k(a,b,c,0,0,0)
#else
static __device__ __forceinline__ f32x4 MFMA16(bf16x4 a, bf16x4 b, f32x4 c){
    f32x4 d;
    asm("v_mfma_f32_16x16x16_bf16 %0, %1, %2, %3" : "=v"(d) : "v"(a), "v"(b), "v"(c));
    return d;
}
#endif

__device__ __forceinline__ short f2b(float f){
    unsigned u = __builtin_bit_cast(unsigned, f);
    u = (u + 0x7FFFu + ((u >> 16) & 1u)) >> 16;
    return (short)u;
}
__device__ __forceinline__ float gelu_f(float v) {
    float u = 0.7978845608028654f * (v + 0.044715f * v * v * v);
    float e = __expf(2.0f * u);
    float t = 1.0f - 2.0f / (e + 1.0f);
    return 0.5f * v * (1.0f + t);
}
__device__ __forceinline__ bf16x4 cvt4(f32x4 v){
    bf16x4 o;
    #pragma unroll
    for (int i=0;i<4;i++) o[i]=f2b(v[i]);
    return o;
}

// ======== kern0: precompute bf16 tables ========
__global__ __launch_bounds__(256) void kern0(
    const float* __restrict__ Lw1, const float* __restrict__ Lb1, const float* __restrict__ Lw2,
    const float* __restrict__ Gw1, const float* __restrict__ Gb1, const float* __restrict__ Gw2,
    const float* __restrict__ uw,
    const float* __restrict__ Wuw, const float* __restrict__ Huw,
    const float* __restrict__ Msw, const float* __restrict__ Msb,
    const float* __restrict__ ow,
    short* __restrict__ G1a, short* __restrict__ L1a,
    short* __restrict__ G2T, short* __restrict__ L2T,
    short* __restrict__ WuT, short* __restrict__ HuT,
    short* __restrict__ owT, short* __restrict__ uwT, short* __restrict__ MsA,
    short* __restrict__ basisW, short* __restrict__ basis2P)
{
    const int bid = blockIdx.x, t = threadIdx.x;
    const float tp = 6.28318530717958648f/256.f;
    if (bid == 0){
        for (int idx=t; idx<1024; idx+=256){
            int o = idx>>5, c = idx&31;
            WuT[o*32+c] = f2b(Wuw[c*32+o]);
        }
    } else if (bid == 1){
        for (int idx=t; idx<1024; idx+=256){
            int o = idx>>5, c = idx&31;
            HuT[o*32+c] = f2b(Huw[c*32+o]);
        }
    } else if (bid == 2){
        for (int idx=t; idx<1024; idx+=256){
            int hd = idx>>4, k2 = idx&15;
            G1a[idx] = f2b(k2<4 ? Gw1[k2*64+hd] : (k2==4 ? Gb1[hd] : 0.f));
            L1a[idx] = f2b(k2<4 ? Lw1[k2*64+hd] : (k2==4 ? Lb1[hd] : 0.f));
        }
    } else if (bid == 3){
        for (int idx=t; idx<2048; idx+=256){ int o=idx>>6, m=idx&63; G2T[idx]=f2b(Gw2[m*32+o]); }
    } else if (bid == 4){
        for (int idx=t; idx<2048; idx+=256){ int o=idx>>6, m=idx&63; L2T[idx]=f2b(Lw2[m*32+o]); }
    } else if (bid == 5){
        for (int idx=t; idx<1024; idx+=256){
            int o=idx>>5, c=idx&31;
            owT[idx]=f2b(ow[c*32+o]);
            uwT[idx]=f2b(uw[c*32+o]);
        }
    } else if (bid == 6){
        for (int idx=t; idx<512; idx+=256){
            int o=idx>>4, k2=idx&15;
            MsA[idx]=f2b(k2<4 ? Msw[k2*32+o] : (k2==4 ? Msb[o] : 0.f));
        }
    } else if (bid < 15){
        int base=(bid-7)*1024;
        for (int i=t; i<1024; i+=256){
            int idx=base+i; int m=idx>>8, w=idx&255;
            float v=0.f;
            if (m<12)       v = cosf(tp*(float)((m*w)&255));
            else if (m<24)  v = sinf(tp*(float)(((m-12)*w)&255));
            basisW[idx]=f2b(v);
        }
    } else if (bid < 23){
        int base=(bid-15)*1024;
        for (int i=t; i<1024; i+=256){
            int idx=base+i; int w=idx>>5, k=idx&31;
            float v=0.f;
            if (k<24){ int m=k>>1; float a=tp*(float)((m*w)&255); v=(k&1)? -sinf(a):cosf(a); }
            basis2P[idx]=f2b(v);
        }
    }
}

// ======== kernA: 512 thr, 2 rows/block. v^T chain + w-DFT; optionally emit uT ========
template<bool USEU>
__global__ __launch_bounds__(512, 3) void kernA(
    const float* __restrict__ x, const float* __restrict__ kk,
    const float* __restrict__ Lb2, const float* __restrict__ ubv,
    const short* __restrict__ L1a, const short* __restrict__ L2T,
    const short* __restrict__ uwT, const short* __restrict__ MsA,
    const short* __restrict__ basisW, float* __restrict__ A1,
    short* __restrict__ uTg)
{
    __shared__ short vT[2][32*264];   // [row][ch][pixel] padded
    const int tid = threadIdx.x, l = tid&63, wva = tid>>6;
    const int row = wva>>2, wv = wva&3;
    const int bh = blockIdx.x*2 + row, b = bh>>8, h = bh&255;
    const int q = l>>4, r = l&15;
    const f32x4 z4 = {0.f,0.f,0.f,0.f};

    // hoisted per-lane biases
    float4 lb2v[2], ubv4[2];
    #pragma unroll
    for (int mt=0; mt<2; mt++){
        lb2v[mt] = *(const float4*)(Lb2 + 16*mt + 4*q);
        ubv4[mt] = *(const float4*)(ubv + 16*mt + 4*q);
    }

    // B-fragments: k (bias-augmented) and x
    bf16x4 kB[4], xB[4][2];
    #pragma unroll
    for (int nt=0; nt<4; nt++){
        int p = wv*64 + nt*16 + r;
        bf16x4 tkn = {0,0,0,0};
        if (q==0){
            float4 k4 = *(const float4*)(kk + ((size_t)bh*256+p)*4);
            tkn = cvt4((f32x4){k4.x,k4.y,k4.z,k4.w});
        } else if (q==1){ tkn[0] = (short)0x3F80; }
        kB[nt]=tkn;
        #pragma unroll
        for (int ks=0; ks<2; ks++){
            float4 x4 = *(const float4*)(x + ((size_t)bh*256+p)*32 + 16*ks + 4*q);
            xB[nt][ks] = cvt4((f32x4){x4.x,x4.y,x4.z,x4.w});
        }
    }

    // hidden = gelu(k@Lw1 + Lb1) as B-fragments
    bf16x4 hidB[4][4];
    #pragma unroll
    for (int mt=0; mt<4; mt++){
        bf16x4 la = *(const bf16x4*)(L1a + (r+16*mt)*16 + 4*q);
        #pragma unroll
        for (int nt=0; nt<4; nt++){
            f32x4 acc = MFMA16(la, kB[nt], z4);
            f32x4 g;
            #pragma unroll
            for (int i=0;i<4;i++) g[i]=gelu_f(acc[i]);
            hidB[mt][nt] = cvt4(g);
        }
    }

    // L^T, u^T, Ms^T -> v^T -> LDS ; also uT -> global (bf16)
    #pragma unroll
    for (int mt=0; mt<2; mt++){
        bf16x4 ma  = *(const bf16x4*)(MsA + (r+16*mt)*16 + 4*q);
        bf16x4 ua0 = *(const bf16x4*)(uwT + (r+16*mt)*32 + 4*q);
        bf16x4 ua1 = *(const bf16x4*)(uwT + (r+16*mt)*32 + 16 + 4*q);
        bf16x4 l2f[4];
        #pragma unroll
        for (int ks=0; ks<4; ks++)
            l2f[ks] = *(const bf16x4*)(L2T + (r+16*mt)*64 + 16*ks + 4*q);
        #pragma unroll
        for (int nt=0; nt<4; nt++){
            f32x4 aU = MFMA16(ua0, xB[nt][0], z4);
            aU = MFMA16(ua1, xB[nt][1], aU);
            f32x4 aM = MFMA16(ma, kB[nt], z4);
            f32x4 aL = z4;
            #pragma unroll
            for (int ks=0; ks<4; ks++) aL = MFMA16(l2f[ks], hidB[ks][nt], aL);
            f32x4 ub4;
            #pragma unroll
            for (int rg=0; rg<4; rg++) ub4[rg] = aU[rg] + ((const float*)&ubv4[mt])[rg];
            if (USEU){
                *(bf16x4*)(uTg + ((size_t)bh*256 + wv*64 + nt*16 + r)*32 + 16*mt + 4*q) = cvt4(ub4);
            }
            #pragma unroll
            for (int rg=0; rg<4; rg++){
                int ch = 16*mt + 4*q + rg;
                float v = (aL[rg] + ((const float*)&lb2v[mt])[rg]) * ub4[rg] + aM[rg];
                vT[row][ch*264 + wv*64 + nt*16 + r] = f2b(v);
            }
        }
    }
    __syncthreads();

    // w-DFT: C[mode][ch] = sum_w basisW[mode][w] * v^T[ch][w]
    const int mt2 = wv>>1, nt2 = wv&1;
    f32x4 accD = z4;
    #pragma unroll
    for (int ks=0; ks<8; ks++){
        bf16x8 av = *(const bf16x8*)(basisW + (r+16*mt2)*256 + 32*ks + 8*q);
        bf16x8 bv = *(const bf16x8*)(&vT[row][(r+16*nt2)*264 + 32*ks + 8*q]);
        accD = MFMA32(av, bv, accD);
    }
    #pragma unroll
    for (int rg=0; rg<4; rg++){
        int mode = 16*mt2 + 4*q + rg;
        int ch = r + 16*nt2;
        if (mode < 12)
            A1[((size_t)(b*12+mode)*256 + h)*64 + ch*2] = accD[rg];
        else if (mode < 24)
            A1[((size_t)(b*12+mode-12)*256 + h)*64 + ch*2 + 1] = -accD[rg];
    }
}

// ======== kernC: h-DFT, spectral multiply, inverse h-DFT -> bf16 Tp ========
__global__ __launch_bounds__(256) void kernC(
    const float* __restrict__ A1,
    const float* __restrict__ k1r, const float* __restrict__ k1i,
    const float* __restrict__ k2r, const float* __restrict__ k2i,
    short* __restrict__ Tp)
{
    __shared__ float vft[NMODE * 64];
    __shared__ float Sm[NMODE * 64];
    __shared__ float ct[256], st[256];

    const int b = blockIdx.x / 12;
    const int j = blockIdx.x % 12;
    const int t = threadIdx.x;

    __sincosf(0.0245436926066f * (float)t, &st[t], &ct[t]);
    __syncthreads();

    const float* ag = A1 + (size_t)(b*12 + j) * 16384;
    const int c  = t & 31;
    const int i0 = t >> 5;

    {
        const int ia0 = i0;
        const int ia1 = (i0 + 8 < 12) ? (i0 + 8) : (232 + i0 + 8);
        const int ia2 = 232 + i0 + 16;
        float r0=0,m0=0, r1=0,m1=0, r2=0,m2=0;
        #pragma unroll 4
        for (int hh = 0; hh < 256; hh++) {
            float2 av = *reinterpret_cast<const float2*>(ag + hh*64 + c*2);
            int p0 = (ia0*hh) & 255; float c0 = ct[p0], s0 = st[p0];
            int p1 = (ia1*hh) & 255; float c1 = ct[p1], s1 = st[p1];
            int p2 = (ia2*hh) & 255; float c2 = ct[p2], s2 = st[p2];
            r0 += av.x*c0 + av.y*s0;  m0 += av.y*c0 - av.x*s0;
            r1 += av.x*c1 + av.y*s1;  m1 += av.y*c1 - av.x*s1;
            r2 += av.x*c2 + av.y*s2;  m2 += av.y*c2 - av.x*s2;
        }
        vft[(i0      *32 + c)*2] = r0; vft[(i0      *32 + c)*2 + 1] = m0;
        vft[((i0+8 ) *32 + c)*2] = r1; vft[((i0+8 ) *32 + c)*2 + 1] = m1;
        vft[((i0+16) *32 + c)*2] = r2; vft[((i0+16) *32 + c)*2 + 1] = m2;
    }
    __syncthreads();

    {
        const int o = t & 31;
        const float* wr0 = k1r;                  const float* wi0 = k1i;                  const int ii0 = i0;
        const float* wr1 = (i0+8 < 12) ? k1r : k2r;
        const float* wi1 = (i0+8 < 12) ? k1i : k2i;
        const int    ii1 = (i0+8 < 12) ? (i0+8) : (i0-4);
        const float* wr2 = k2r;                  const float* wi2 = k2i;                  const int ii2 = i0 + 4;
        float r0=0,m0=0, r1=0,m1=0, r2=0,m2=0;
        #pragma unroll
        for (int cc = 0; cc < 32; cc++) {
            float vr0 = vft[(i0      *32 + cc)*2], vi0 = vft[(i0      *32 + cc)*2 + 1];
            float vr1 = vft[((i0+8 ) *32 + cc)*2], vi1 = vft[((i0+8 ) *32 + cc)*2 + 1];
            float vr2 = vft[((i0+16) *32 + cc)*2], vi2 = vft[((i0+16) *32 + cc)*2 + 1];
            size_t base = (size_t)(cc*32 + o) * 144 + j;
            float kr0 = wr0[base + (size_t)ii0*12], ki0 = wi0[base + (size_t)ii0*12];
            float kr1 = wr1[base + (size_t)ii1*12], ki1 = wi1[base + (size_t)ii1*12];
            float kr2 = wr2[base + (size_t)ii2*12], ki2 = wi2[base + (size_t)ii2*12];
            r0 += vr0*kr0 - vi0*ki0;  m0 += vr0*ki0 + vi0*kr0;
            r1 += vr1*kr1 - vi1*ki1;  m1 += vr1*ki1 + vi1*kr1;
            r2 += vr2*kr2 - vi2*ki2;  m2 += vr2*ki2 + vi2*kr2;
        }
        Sm[(i0      *32 + o)*2] = r0; Sm[(i0      *32 + o)*2 + 1] = m0;
        Sm[((i0+8 ) *32 + o)*2] = r1; Sm[((i0+8 ) *32 + o)*2 + 1] = m1;
        Sm[((i0+16) *32 + o)*2] = r2; Sm[((i0+16) *32 + o)*2 + 1] = m2;
    }
    __syncthreads();

    {
        float Tre[32], Tim[32];
        #pragma unroll
        for (int o = 0; o < 32; o++) { Tre[o] = 0.f; Tim[o] = 0.f; }
        #pragma unroll 4
        for (int m = 0; m < 24; m++) {
            int iam = (m < 12) ? m : (232 + m);
            int ph = (iam * t) & 255;
            float cc2 = ct[ph], ss2 = st[ph];
            #pragma unroll
            for (int o = 0; o < 32; o++) {
                float sr = Sm[(m*32 + o)*2], si = Sm[(m*32 + o)*2 + 1];
                Tre[o] += sr*cc2 - si*ss2;
                Tim[o] += sr*ss2 + si*cc2;
            }
        }
        const float sc = (j == 0) ? (1.0f/65536.0f) : (2.0f/65536.0f);
        short* dst = Tp + ((size_t)(b*256 + t))*1024;   // [o][32]
        #pragma unroll
        for (int o = 0; o < 32; o++) {
            dst[o*32 + 2*j]     = f2b(Tre[o] * sc);
            dst[o*32 + 2*j + 1] = f2b(Tim[o] * sc);
        }
        if (j == 0){
            #pragma unroll
            for (int o = 0; o < 32; o++)
                #pragma unroll
                for (int kp = 24; kp < 32; kp++) dst[o*32 + kp] = 0;
        }
    }
}

// ======== kernD: 512 thr, 2 rows/block, in-register chain, no LDS/barriers ========
template<bool USEU>
__global__ __launch_bounds__(512, 4) void kernD(
    const float* __restrict__ x, const float* __restrict__ kk,
    const float* __restrict__ Gb2, const float* __restrict__ obv,
    const float* __restrict__ Wub, const float* __restrict__ Hub,
    const float* __restrict__ ubv, const float* __restrict__ uw,
    const short* __restrict__ G1a, const short* __restrict__ G2T,
    const short* __restrict__ WuT, const short* __restrict__ HuT,
    const short* __restrict__ owT, const short* __restrict__ basis2P,
    const short* __restrict__ Tp, const short* __restrict__ uTg,
    float* __restrict__ out)
{
    const int tid = threadIdx.x, l = tid&63, wva = tid>>6;
    const int row = wva>>2, wv = wva&3;
    const int bh = blockIdx.x*2 + row;
    const int q = l>>4, r = l&15;
    const f32x4 z4 = {0.f,0.f,0.f,0.f};

    // hoisted per-lane biases
    float4 gb2v[2], obv2[2], wubv[2], hubv[2];
    #pragma unroll
    for (int mt=0; mt<2; mt++){
        gb2v[mt] = *(const float4*)(Gb2 + 16*mt + 4*q);
        obv2[mt] = *(const float4*)(obv + 16*mt + 4*q);
        wubv[mt] = *(const float4*)(Wub + 16*mt + 4*q);
        hubv[mt] = *(const float4*)(Hub + 16*mt + 4*q);
    }

    // k and u fragments
    bf16x4 kB[4], uB[4][2];
    #pragma unroll
    for (int nt=0; nt<4; nt++){
        int p = wv*64 + nt*16 + r;
        bf16x4 tkn = {0,0,0,0};
        if (q==0){
            float4 k4 = *(const float4*)(kk + ((size_t)bh*256+p)*4);
            tkn = cvt4((f32x4){k4.x,k4.y,k4.z,k4.w});
        } else if (q==1){ tkn[0] = (short)0x3F80; }
        kB[nt]=tkn;
        if (USEU){
            #pragma unroll
            for (int ks=0; ks<2; ks++)
                uB[nt][ks] = *(const bf16x4*)(uTg + ((size_t)bh*256 + p)*32 + 16*ks + 4*q);
        }
    }
    if (!USEU){
        // fallback: compute u = x@uw + ub via MFMA, then repack C-frag -> B-frag (same mapping)
        bf16x4 xB[4][2];
        #pragma unroll
        for (int nt=0; nt<4; nt++){
            int p = wv*64 + nt*16 + r;
            #pragma unroll
            for (int ks=0; ks<2; ks++){
                float4 x4 = *(const float4*)(x + ((size_t)bh*256+p)*32 + 16*ks + 4*q);
                xB[nt][ks] = cvt4((f32x4){x4.x,x4.y,x4.z,x4.w});
            }
        }
        float4 ubv4[2];
        #pragma unroll
        for (int mt=0; mt<2; mt++) ubv4[mt] = *(const float4*)(ubv + 16*mt + 4*q);
        #pragma unroll
        for (int mt=0; mt<2; mt++){
            bf16x4 ua0, ua1;
            {
                f32x4 t0, t1;
                #pragma unroll
                for (int e=0;e<4;e++){
                    t0[e] = uw[(4*q+e)*32 + (r+16*mt)];
                    t1[e] = uw[(16+4*q+e)*32 + (r+16*mt)];
                }
                ua0 = cvt4(t0); ua1 = cvt4(t1);
            }
            #pragma unroll
            for (int nt=0; nt<4; nt++){
                f32x4 aU = MFMA16(ua0, xB[nt][0], z4);
                aU = MFMA16(ua1, xB[nt][1], aU);
                #pragma unroll
                for (int rg=0; rg<4; rg++) aU[rg] += ((const float*)&ubv4[mt])[rg];
                uB[nt][mt] = cvt4(aU);
            }
        }
    }

    // hidden = gelu(k@Gw1 + Gb1) as B-fragments
    bf16x4 hidB[4][4];
    #pragma unroll
    for (int mt=0; mt<4; mt++){
        bf16x4 ga = *(const bf16x4*)(G1a + (r+16*mt)*16 + 4*q);
        #pragma unroll
        for (int nt=0; nt<4; nt++){
            f32x4 acc = MFMA16(ga, kB[nt], z4);
            f32x4 g;
            #pragma unroll
            for (int i=0;i<4;i++) g[i]=gelu_f(acc[i]);
            hidB[mt][nt] = cvt4(g);
        }
    }

    // Fv^T = Tp(bh) @ basis2P^T
    f32x4 aF[2][4];
    {
        bf16x4 bb[4][2];
        #pragma unroll
        for (int nt=0; nt<4; nt++){
            int p = wv*64 + nt*16 + r;
            bb[nt][0] = *(const bf16x4*)(basis2P + p*32 + 4*q);
            bb[nt][1] = *(const bf16x4*)(basis2P + p*32 + 16 + 4*q);
        }
        #pragma unroll
        for (int mt=0; mt<2; mt++){
            bf16x4 t0 = *(const bf16x4*)(Tp + (size_t)bh*1024 + (r+16*mt)*32 + 4*q);
            bf16x4 t1 = *(const bf16x4*)(Tp + (size_t)bh*1024 + (r+16*mt)*32 + 16 + 4*q);
            #pragma unroll
            for (int nt=0; nt<4; nt++){
                f32x4 acc = MFMA16(t0, bb[nt][0], z4);
                aF[mt][nt] = MFMA16(t1, bb[nt][1], acc);
            }
        }
    }

    // aF := (Hu + Hub) - Fv
    #pragma unroll
    for (int mt=0; mt<2; mt++){
        bf16x4 h0 = *(const bf16x4*)(HuT + (r+16*mt)*32 + 4*q);
        bf16x4 h1 = *(const bf16x4*)(HuT + (r+16*mt)*32 + 16 + 4*q);
        #pragma unroll
        for (int nt=0; nt<4; nt++){
            f32x4 aHu = MFMA16(h0, uB[nt][0], z4);
            aHu = MFMA16(h1, uB[nt][1], aHu);
            #pragma unroll
            for (int rg=0; rg<4; rg++)
                aF[mt][nt][rg] = (aHu[rg] + ((const float*)&hubv[mt])[rg]) - aF[mt][nt][rg];
        }
    }

    // aF := (G + Gb2) * aF
    #pragma unroll
    for (int mt=0; mt<2; mt++){
        bf16x4 g2[4];
        #pragma unroll
        for (int ks=0; ks<4; ks++)
            g2[ks] = *(const bf16x4*)(G2T + (r+16*mt)*64 + 16*ks + 4*q);
        #pragma unroll
        for (int nt=0; nt<4; nt++){
            f32x4 aG = z4;
            #pragma unroll
            for (int ks=0; ks<4; ks++) aG = MFMA16(g2[ks], hidB[ks][nt], aG);
            #pragma unroll
            for (int rg=0; rg<4; rg++)
                aF[mt][nt][rg] = (aG[rg] + ((const float*)&gb2v[mt])[rg]) * aF[mt][nt][rg];
        }
    }

    // born = (Wu + Wub) - aF  -> B-fragments
    bf16x4 bornB[2][4];
    #pragma unroll
    for (int mt=0; mt<2; mt++){
        bf16x4 w0 = *(const bf16x4*)(WuT + (r+16*mt)*32 + 4*q);
        bf16x4 w1 = *(const bf16x4*)(WuT + (r+16*mt)*32 + 16 + 4*q);
        #pragma unroll
        for (int nt=0; nt<4; nt++){
            f32x4 aW = MFMA16(w0, uB[nt][0], z4);
            aW = MFMA16(w1, uB[nt][1], aW);
            f32x4 brn;
            #pragma unroll
            for (int rg=0; rg<4; rg++)
                brn[rg] = (aW[rg] + ((const float*)&wubv[mt])[rg]) - aF[mt][nt][rg];
            bornB[mt][nt] = cvt4(brn);
        }
    }

    // out = gelu(born @ ow + ob)
    #pragma unroll
    for (int mt=0; mt<2; mt++){
        bf16x4 o0 = *(const bf16x4*)(owT + (r+16*mt)*32 + 4*q);
        bf16x4 o1 = *(const bf16x4*)(owT + (r+16*mt)*32 + 16 + 4*q);
        #pragma unroll
        for (int nt=0; nt<4; nt++){
            f32x4 aO = MFMA16(o0, bornB[0][nt], z4);
            aO = MFMA16(o1, bornB[1][nt], aO);
            float4 res;
            res.x = gelu_f(aO[0] + obv2[mt].x);
            res.y = gelu_f(aO[1] + obv2[mt].y);
            res.z = gelu_f(aO[2] + obv2[mt].z);
            res.w = gelu_f(aO[3] + obv2[mt].w);
            *(float4*)(out + ((size_t)bh*256 + wv*64 + nt*16 + r)*32 + 16*mt + 4*q) = res;
        }
    }
}

extern "C" void kernel_launch(void* const* d_in, const int* in_sizes, int n_in,
                              void* d_out, int out_size, void* d_ws, size_t ws_size,
                              hipStream_t stream)
{
    const float* x   = (const float*)d_in[0];
    const float* kk  = (const float*)d_in[1];
    const float* Lw1 = (const float*)d_in[2];
    const float* Lb1 = (const float*)d_in[3];
    const float* Lw2 = (const float*)d_in[4];
    const float* Lb2 = (const float*)d_in[5];
    const float* Gw1 = (const float*)d_in[6];
    const float* Gb1 = (const float*)d_in[7];
    const float* Gw2 = (const float*)d_in[8];
    const float* Gb2 = (const float*)d_in[9];
    const float* uw  = (const float*)d_in[10];
    const float* ub  = (const float*)d_in[11];
    const float* Wuw = (const float*)d_in[12];
    const float* Wub = (const float*)d_in[13];
    const float* Huw = (const float*)d_in[14];
    const float* Hub = (const float*)d_in[15];
    const float* Msw = (const float*)d_in[16];
    const float* Msb = (const float*)d_in[17];
    const float* ow  = (const float*)d_in[18];
    const float* ob  = (const float*)d_in[19];
    const float* k1r = (const float*)d_in[20];
    const float* k1i = (const float*)d_in[21];
    const float* k2r = (const float*)d_in[22];
    const float* k2i = (const float*)d_in[23];

    float* A1 = (float*)d_ws;                 // 1,572,864 floats (6 MB)
    short* Tp = (short*)(A1 + 1572864);       // 2,097,152 shorts (4 MB)
    short* tab = Tp + 2097152;
    short* G1a  = tab;              // 1024
    short* L1a  = G1a + 1024;       // 1024
    short* G2T  = L1a + 1024;       // 2048
    short* L2T  = G2T + 2048;       // 2048
    short* WuT  = L2T + 2048;       // 1024
    short* HuT  = WuT + 1024;       // 1024
    short* owT  = HuT + 1024;       // 1024
    short* uwT  = owT + 1024;       // 1024
    short* MsA  = uwT + 1024;       // 512
    short* basisW  = MsA + 512;     // 8192
    short* basis2P = basisW + 8192; // 8192
    short* uTg = basis2P + 8192;    // 16,777,216 shorts (33.5 MB)

    size_t need = (size_t)((char*)(uTg + 16777216) - (char*)d_ws);
    bool useU = ws_size >= need;

    float* outp = (float*)d_out;

    kern0<<<23, 256, 0, stream>>>(Lw1, Lb1, Lw2, Gw1, Gb1, Gw2, uw,
                                  Wuw, Huw, Msw, Msb, ow,
                                  G1a, L1a, G2T, L2T, WuT, HuT, owT, uwT, MsA,
                                  basisW, basis2P);
    if (useU){
        kernA<true><<<BB*128, 512, 0, stream>>>(x, kk, Lb2, ub, L1a, L2T, uwT, MsA, basisW, A1, uTg);
    } else {
        kernA<false><<<BB*128, 512, 0, stream>>>(x, kk, Lb2, ub, L1a, L2T, uwT, MsA, basisW, A1, uTg);
    }
    kernC<<<BB*12, 256, 0, stream>>>(A1, k1r, k1i, k2r, k2i, Tp);
    if (useU){
        kernD<true><<<BB*128, 512, 0, stream>>>(x, kk, Gb2, ob, Wub, Hub, ub, uw,
                                                G1a, G2T, WuT, HuT, owT, basis2P, Tp, uTg, outp);
    } else {
        kernD<false><<<BB*128, 512, 0, stream>>>(x, kk, Gb2, ob, Wub, Hub, ub, uw,
                                                 G1a, G2T, WuT, HuT, owT, basis2P, Tp, uTg, outp);
    }
}

// Round 6
// 151.081 us; speedup vs baseline: 1.4213x; 1.3093x over previous
//
#include <hip/hip_runtime.h>
#include <math.h>

#define BB 8
#define NMODE 24

typedef __attribute__((ext_vector_type(8))) short bf16x8;
typedef __attribute__((ext_vector_type(4))) short bf16x4;
typedef __attribute__((ext_vector_type(4))) float f32x4;

#define MFMA32(a,b,c) __builtin_amdgcn_mfma_f32_16x16x32_bf16(a,b,c,0,0,0)

#if __has_builtin(__builtin_amdgcn_mfma_f32_16x16x16bf16_1k)
#define MFMA16(a,b,c) __builtin_amdgcn_mfma_f32_16x16x16bf16_1k(a,b,c,0,0,0)
#else
static __device__ __forceinline__ f32x4 MFMA16(bf16x4 a, bf16x4 b, f32x4 c){
    f32x4 d;
    asm("v_mfma_f32_16x16x16_bf16 %0, %1, %2, %3" : "=v"(d) : "v"(a), "v"(b), "v"(c));
    return d;
}
#endif

__device__ __forceinline__ short f2b(float f){
    unsigned u = __builtin_bit_cast(unsigned, f);
    u = (u + 0x7FFFu + ((u >> 16) & 1u)) >> 16;
    return (short)u;
}
__device__ __forceinline__ float b2f(short s){
    unsigned u = ((unsigned)(unsigned short)s) << 16;
    return __builtin_bit_cast(float, u);
}
__device__ __forceinline__ float gelu_f(float v) {
    float u = 0.7978845608028654f * (v + 0.044715f * v * v * v);
    float e = __expf(2.0f * u);
    float t = 1.0f - 2.0f / (e + 1.0f);
    return 0.5f * v * (1.0f + t);
}
__device__ __forceinline__ bf16x4 cvt4(f32x4 v){
    bf16x4 o;
    #pragma unroll
    for (int i=0;i<4;i++) o[i]=f2b(v[i]);
    return o;
}

// ======== kern0: precompute bf16 tables ========
__global__ __launch_bounds__(256) void kern0(
    const float* __restrict__ Lw1, const float* __restrict__ Lb1, const float* __restrict__ Lw2,
    const float* __restrict__ Gw1, const float* __restrict__ Gb1, const float* __restrict__ Gw2,
    const float* __restrict__ uw,
    const float* __restrict__ Wuw, const float* __restrict__ Huw,
    const float* __restrict__ Msw, const float* __restrict__ Msb,
    const float* __restrict__ ow,
    const float* __restrict__ k1r, const float* __restrict__ k1i,
    const float* __restrict__ k2r, const float* __restrict__ k2i,
    short* __restrict__ G1a, short* __restrict__ L1a,
    short* __restrict__ G2T, short* __restrict__ L2T,
    short* __restrict__ WuT, short* __restrict__ HuT,
    short* __restrict__ owT, short* __restrict__ uwT, short* __restrict__ MsA,
    short* __restrict__ basisW, short* __restrict__ basis2P,
    short* __restrict__ basisH1, short* __restrict__ basisH3,
    short* __restrict__ Kp)
{
    const int bid = blockIdx.x, t = threadIdx.x;
    const float tp = 6.28318530717958648f/256.f;
    if (bid == 0){
        for (int idx=t; idx<1024; idx+=256){
            int o = idx>>5, c = idx&31;
            WuT[o*32+c] = f2b(Wuw[c*32+o]);
        }
    } else if (bid == 1){
        for (int idx=t; idx<1024; idx+=256){
            int o = idx>>5, c = idx&31;
            HuT[o*32+c] = f2b(Huw[c*32+o]);
        }
    } else if (bid == 2){
        for (int idx=t; idx<1024; idx+=256){
            int hd = idx>>4, k2 = idx&15;
            G1a[idx] = f2b(k2<4 ? Gw1[k2*64+hd] : (k2==4 ? Gb1[hd] : 0.f));
            L1a[idx] = f2b(k2<4 ? Lw1[k2*64+hd] : (k2==4 ? Lb1[hd] : 0.f));
        }
    } else if (bid == 3){
        for (int idx=t; idx<2048; idx+=256){ int o=idx>>6, m=idx&63; G2T[idx]=f2b(Gw2[m*32+o]); }
    } else if (bid == 4){
        for (int idx=t; idx<2048; idx+=256){ int o=idx>>6, m=idx&63; L2T[idx]=f2b(Lw2[m*32+o]); }
    } else if (bid == 5){
        for (int idx=t; idx<1024; idx+=256){
            int o=idx>>5, c=idx&31;
            owT[idx]=f2b(ow[c*32+o]);
            uwT[idx]=f2b(uw[c*32+o]);
        }
    } else if (bid == 6){
        for (int idx=t; idx<512; idx+=256){
            int o=idx>>4, k2=idx&15;
            MsA[idx]=f2b(k2<4 ? Msw[k2*32+o] : (k2==4 ? Msb[o] : 0.f));
        }
    } else if (bid < 15){
        int base=(bid-7)*1024;
        for (int i=t; i<1024; i+=256){
            int idx=base+i; int m=idx>>8, w=idx&255;
            float v=0.f;
            if (m<12)       v = cosf(tp*(float)((m*w)&255));
            else if (m<24)  v = sinf(tp*(float)(((m-12)*w)&255));
            basisW[idx]=f2b(v);
        }
    } else if (bid < 23){
        int base=(bid-15)*1024;
        for (int i=t; i<1024; i+=256){
            int idx=base+i; int w=idx>>5, k=idx&31;
            float v=0.f;
            if (k<24){ int m=k>>1; float a=tp*(float)((m*w)&255); v=(k&1)? -sinf(a):cosf(a); }
            basis2P[idx]=f2b(v);
        }
    } else if (bid < 27){
        // basisH1 [48 rows][256 h]: rows 0-23 cos(ia_m h), 24-47 sin(ia_m h)
        int base=(bid-23)*3072;
        for (int i=t; i<3072; i+=256){
            int idx=base+i; int m = idx>>8, h = idx&255;
            int mm = m % 24;
            int ia = (mm<12) ? mm : 232+mm;
            float a = tp*(float)((ia*h)&255);
            basisH1[idx] = f2b(m<24 ? cosf(a) : sinf(a));
        }
    } else if (bid < 35){
        // basisH3 [256 h][64 k]: k<24 cos(ia_k h), 24-47 sin, 48-63 zero
        int base=(bid-27)*2048;
        for (int i=t; i<2048; i+=256){
            int idx=base+i; int h = idx>>6, k = idx&63;
            float v = 0.f;
            if (k < 48){
                int mm = k % 24;
                int ia = (mm<12) ? mm : 232+mm;
                float a = tp*(float)((ia*h)&255);
                v = (k<24) ? cosf(a) : sinf(a);
            }
            basisH3[idx] = f2b(v);
        }
    } else {
        // Kp [j 12][ii 24][c 32][o 32][2] bf16, scale folded: 294912 pairs
        int base=(bid-35)*8192;
        for (int i=t; i<8192; i+=256){
            int pid = base + i;
            int o = pid & 31, c = (pid>>5) & 31;
            int rest = pid >> 10;         // jj*24 + ii
            int ii = rest % 24, jj = rest / 24;
            int iis = (ii<12) ? ii : ii-12;
            const float* wr = (ii<12) ? k1r : k2r;
            const float* wi = (ii<12) ? k1i : k2i;
            size_t widx = ((size_t)(c*32 + o)*12 + iis)*12 + jj;
            float sc = (jj==0 ? 1.f : 2.f) / 65536.f;
            Kp[2*pid]   = f2b(wr[widx] * sc);
            Kp[2*pid+1] = f2b(wi[widx] * sc);
        }
    }
}

// ======== kernA: 512 thr, 2 rows/block. v^T chain + w-DFT; optionally emit uT ========
template<bool USEU>
__global__ __launch_bounds__(512, 3) void kernA(
    const float* __restrict__ x, const float* __restrict__ kk,
    const float* __restrict__ Lb2, const float* __restrict__ ubv,
    const short* __restrict__ L1a, const short* __restrict__ L2T,
    const short* __restrict__ uwT, const short* __restrict__ MsA,
    const short* __restrict__ basisW, float* __restrict__ A1,
    short* __restrict__ uTg)
{
    __shared__ short vT[2][32*264];   // [row][ch][pixel] padded
    const int tid = threadIdx.x, l = tid&63, wva = tid>>6;
    const int row = wva>>2, wv = wva&3;
    const int bh = blockIdx.x*2 + row, b = bh>>8, h = bh&255;
    const int q = l>>4, r = l&15;
    const f32x4 z4 = {0.f,0.f,0.f,0.f};

    float4 lb2v[2], ubv4[2];
    #pragma unroll
    for (int mt=0; mt<2; mt++){
        lb2v[mt] = *(const float4*)(Lb2 + 16*mt + 4*q);
        ubv4[mt] = *(const float4*)(ubv + 16*mt + 4*q);
    }

    bf16x4 kB[4], xB[4][2];
    #pragma unroll
    for (int nt=0; nt<4; nt++){
        int p = wv*64 + nt*16 + r;
        bf16x4 tkn = {0,0,0,0};
        if (q==0){
            float4 k4 = *(const float4*)(kk + ((size_t)bh*256+p)*4);
            tkn = cvt4((f32x4){k4.x,k4.y,k4.z,k4.w});
        } else if (q==1){ tkn[0] = (short)0x3F80; }
        kB[nt]=tkn;
        #pragma unroll
        for (int ks=0; ks<2; ks++){
            float4 x4 = *(const float4*)(x + ((size_t)bh*256+p)*32 + 16*ks + 4*q);
            xB[nt][ks] = cvt4((f32x4){x4.x,x4.y,x4.z,x4.w});
        }
    }

    bf16x4 hidB[4][4];
    #pragma unroll
    for (int mt=0; mt<4; mt++){
        bf16x4 la = *(const bf16x4*)(L1a + (r+16*mt)*16 + 4*q);
        #pragma unroll
        for (int nt=0; nt<4; nt++){
            f32x4 acc = MFMA16(la, kB[nt], z4);
            f32x4 g;
            #pragma unroll
            for (int i=0;i<4;i++) g[i]=gelu_f(acc[i]);
            hidB[mt][nt] = cvt4(g);
        }
    }

    #pragma unroll
    for (int mt=0; mt<2; mt++){
        bf16x4 ma  = *(const bf16x4*)(MsA + (r+16*mt)*16 + 4*q);
        bf16x4 ua0 = *(const bf16x4*)(uwT + (r+16*mt)*32 + 4*q);
        bf16x4 ua1 = *(const bf16x4*)(uwT + (r+16*mt)*32 + 16 + 4*q);
        bf16x4 l2f[4];
        #pragma unroll
        for (int ks=0; ks<4; ks++)
            l2f[ks] = *(const bf16x4*)(L2T + (r+16*mt)*64 + 16*ks + 4*q);
        #pragma unroll
        for (int nt=0; nt<4; nt++){
            f32x4 aU = MFMA16(ua0, xB[nt][0], z4);
            aU = MFMA16(ua1, xB[nt][1], aU);
            f32x4 aM = MFMA16(ma, kB[nt], z4);
            f32x4 aL = z4;
            #pragma unroll
            for (int ks=0; ks<4; ks++) aL = MFMA16(l2f[ks], hidB[ks][nt], aL);
            f32x4 ub4;
            #pragma unroll
            for (int rg=0; rg<4; rg++) ub4[rg] = aU[rg] + ((const float*)&ubv4[mt])[rg];
            if (USEU){
                *(bf16x4*)(uTg + ((size_t)bh*256 + wv*64 + nt*16 + r)*32 + 16*mt + 4*q) = cvt4(ub4);
            }
            #pragma unroll
            for (int rg=0; rg<4; rg++){
                int ch = 16*mt + 4*q + rg;
                float v = (aL[rg] + ((const float*)&lb2v[mt])[rg]) * ub4[rg] + aM[rg];
                vT[row][ch*264 + wv*64 + nt*16 + r] = f2b(v);
            }
        }
    }
    __syncthreads();

    const int mt2 = wv>>1, nt2 = wv&1;
    f32x4 accD = z4;
    #pragma unroll
    for (int ks=0; ks<8; ks++){
        bf16x8 av = *(const bf16x8*)(basisW + (r+16*mt2)*256 + 32*ks + 8*q);
        bf16x8 bv = *(const bf16x8*)(&vT[row][(r+16*nt2)*264 + 32*ks + 8*q]);
        accD = MFMA32(av, bv, accD);
    }
    #pragma unroll
    for (int rg=0; rg<4; rg++){
        int mode = 16*mt2 + 4*q + rg;
        int ch = r + 16*nt2;
        if (mode < 12)
            A1[((size_t)(b*12+mode)*256 + h)*64 + ch*2] = accD[rg];
        else if (mode < 24)
            A1[((size_t)(b*12+mode-12)*256 + h)*64 + ch*2 + 1] = -accD[rg];
    }
}

// ======== kernC1: per (b,j): MFMA h-DFT + spectral multiply -> SBg ========
__global__ __launch_bounds__(512) void kernC1(
    const float* __restrict__ A1, const short* __restrict__ basisH1,
    const short* __restrict__ Kp, short* __restrict__ SBg)
{
    __shared__ float C1L[48*66];
    const int bj = blockIdx.x;           // b*12 + j
    const int j  = bj % 12;
    const int tid = threadIdx.x, l = tid&63, w = tid>>6;
    const int q = l>>4, r = l&15;
    const f32x4 z4 = {0.f,0.f,0.f,0.f};

    // stage 1: C1[48][64] = basisH1 @ A1row (bf16 MFMA)
    {
        const float* Ag = A1 + (size_t)bj*16384;
        const int nt  = w & 3;
        const int nmt = (w < 4) ? 2 : 1;
        const int mt0 = (w < 4) ? 0 : 2;
        f32x4 acc[2] = {z4, z4};
        for (int ks=0; ks<8; ks++){
            bf16x8 bv;
            #pragma unroll
            for (int e=0;e<8;e++)
                bv[e] = f2b(Ag[(ks*32 + q*8 + e)*64 + nt*16 + r]);
            #pragma unroll
            for (int mi=0; mi<2; mi++){
                if (mi < nmt){
                    bf16x8 av = *(const bf16x8*)(basisH1 + (r + 16*(mt0+mi))*256 + ks*32 + q*8);
                    acc[mi] = MFMA32(av, bv, acc[mi]);
                }
            }
        }
        #pragma unroll
        for (int mi=0; mi<2; mi++){
            if (mi < nmt){
                #pragma unroll
                for (int rg=0; rg<4; rg++)
                    C1L[(16*(mt0+mi) + 4*q + rg)*66 + 16*nt + r] = acc[mi][rg];
            }
        }
    }
    __syncthreads();

    // stage 2: S[i][o] = sum_c vft[i][c] * K_i[c][o]  (Kp coalesced bf16)
    {
        const int o = tid & 31, g = tid >> 5;   // g in 0..15
        short* SB = SBg + (size_t)bj*4096;
        #pragma unroll
        for (int half=0; half<2; half++){
            int i = g + 16*half;
            if (i < 24){
                float Sre=0.f, Sim=0.f;
                const short* kp = Kp + ((size_t)(j*24 + i)*32)*64 + 2*o;
                #pragma unroll 4
                for (int c=0; c<32; c++){
                    float vr = C1L[i*66 + 2*c]     + C1L[(24+i)*66 + 2*c+1];
                    float vi = C1L[i*66 + 2*c + 1] - C1L[(24+i)*66 + 2*c];
                    short2 kv = *(const short2*)(kp + c*64);
                    float kr = b2f(kv.x), ki = b2f(kv.y);
                    Sre += vr*kr - vi*ki;
                    Sim += vr*ki + vi*kr;
                }
                SB[o*64 + i]           = f2b(Sre);
                SB[o*64 + 24 + i]      = f2b(-Sim);
                SB[2048 + o*64 + i]    = f2b(Sim);
                SB[2048 + o*64 + 24+i] = f2b(Sre);
            }
        }
        // zero k = 48..63, both buffers
        int o2 = (tid >> 4) & 31, kz = 48 + (tid & 15);
        SB[o2*64 + kz] = 0;
        SB[2048 + o2*64 + kz] = 0;
    }
}

// ======== kernC2: per (b, htile): inverse h-DFT for ALL j, dense Tp dump ========
__global__ __launch_bounds__(256) void kernC2(
    const short* __restrict__ basisH3, const short* __restrict__ SBg,
    short* __restrict__ Tp)
{
    __shared__ __align__(16) short Tt[16*1024];   // [h16][o32][k32]
    const int bid = blockIdx.x;         // b*16 + ht
    const int b = bid >> 4, ht = bid & 15;
    const int tid = threadIdx.x, l = tid&63, w = tid>>6;
    const int q = l>>4, r = l&15;
    const f32x4 z4 = {0.f,0.f,0.f,0.f};

    // zero pad cols 24..31
    for (int idx = tid; idx < 512; idx += 256){
        int hh = idx >> 5, o = idx & 31;
        #pragma unroll
        for (int kkz=0; kkz<8; kkz++) Tt[(hh*32+o)*32 + 24 + kkz] = 0;
    }

    bf16x8 af[2];
    #pragma unroll
    for (int ks=0; ks<2; ks++)
        af[ks] = *(const bf16x8*)(basisH3 + (ht*16 + r)*64 + ks*32 + q*8);

    #pragma unroll
    for (int jj=0; jj<3; jj++){
        int j = w*3 + jj;
        const short* SB = SBg + (size_t)(b*12 + j)*4096;
        #pragma unroll
        for (int nt=0; nt<2; nt++){
            f32x4 aRe = z4, aIm = z4;
            #pragma unroll
            for (int ks=0; ks<2; ks++){
                bf16x8 b1 = *(const bf16x8*)(SB + (16*nt + r)*64 + ks*32 + q*8);
                bf16x8 b2 = *(const bf16x8*)(SB + 2048 + (16*nt + r)*64 + ks*32 + q*8);
                aRe = MFMA32(af[ks], b1, aRe);
                aIm = MFMA32(af[ks], b2, aIm);
            }
            #pragma unroll
            for (int rg=0; rg<4; rg++){
                int hl = 4*q + rg, o = 16*nt + r;
                *(short2*)&Tt[(hl*32 + o)*32 + 2*j] = make_short2(f2b(aRe[rg]), f2b(aIm[rg]));
            }
        }
    }
    __syncthreads();

    // coalesced 32 KB dump
    short* dst = Tp + (size_t)(b*256 + ht*16)*1024;
    #pragma unroll
    for (int it=0; it<8; it++){
        int off = (tid + it*256)*8;
        *(int4*)(dst + off) = *(const int4*)&Tt[off];
    }
}

// ======== kernD: 512 thr, 2 rows/block, in-register chain, no LDS/barriers ========
template<bool USEU>
__global__ __launch_bounds__(512, 4) void kernD(
    const float* __restrict__ x, const float* __restrict__ kk,
    const float* __restrict__ Gb2, const float* __restrict__ obv,
    const float* __restrict__ Wub, const float* __restrict__ Hub,
    const float* __restrict__ ubv, const float* __restrict__ uw,
    const short* __restrict__ G1a, const short* __restrict__ G2T,
    const short* __restrict__ WuT, const short* __restrict__ HuT,
    const short* __restrict__ owT, const short* __restrict__ basis2P,
    const short* __restrict__ Tp, const short* __restrict__ uTg,
    float* __restrict__ out)
{
    const int tid = threadIdx.x, l = tid&63, wva = tid>>6;
    const int row = wva>>2, wv = wva&3;
    const int bh = blockIdx.x*2 + row;
    const int q = l>>4, r = l&15;
    const f32x4 z4 = {0.f,0.f,0.f,0.f};

    float4 gb2v[2], obv2[2], wubv[2], hubv[2];
    #pragma unroll
    for (int mt=0; mt<2; mt++){
        gb2v[mt] = *(const float4*)(Gb2 + 16*mt + 4*q);
        obv2[mt] = *(const float4*)(obv + 16*mt + 4*q);
        wubv[mt] = *(const float4*)(Wub + 16*mt + 4*q);
        hubv[mt] = *(const float4*)(Hub + 16*mt + 4*q);
    }

    bf16x4 kB[4], uB[4][2];
    #pragma unroll
    for (int nt=0; nt<4; nt++){
        int p = wv*64 + nt*16 + r;
        bf16x4 tkn = {0,0,0,0};
        if (q==0){
            float4 k4 = *(const float4*)(kk + ((size_t)bh*256+p)*4);
            tkn = cvt4((f32x4){k4.x,k4.y,k4.z,k4.w});
        } else if (q==1){ tkn[0] = (short)0x3F80; }
        kB[nt]=tkn;
        if (USEU){
            #pragma unroll
            for (int ks=0; ks<2; ks++)
                uB[nt][ks] = *(const bf16x4*)(uTg + ((size_t)bh*256 + p)*32 + 16*ks + 4*q);
        }
    }
    if (!USEU){
        bf16x4 xB[4][2];
        #pragma unroll
        for (int nt=0; nt<4; nt++){
            int p = wv*64 + nt*16 + r;
            #pragma unroll
            for (int ks=0; ks<2; ks++){
                float4 x4 = *(const float4*)(x + ((size_t)bh*256+p)*32 + 16*ks + 4*q);
                xB[nt][ks] = cvt4((f32x4){x4.x,x4.y,x4.z,x4.w});
            }
        }
        float4 ubv4[2];
        #pragma unroll
        for (int mt=0; mt<2; mt++) ubv4[mt] = *(const float4*)(ubv + 16*mt + 4*q);
        #pragma unroll
        for (int mt=0; mt<2; mt++){
            bf16x4 ua0, ua1;
            {
                f32x4 t0, t1;
                #pragma unroll
                for (int e=0;e<4;e++){
                    t0[e] = uw[(4*q+e)*32 + (r+16*mt)];
                    t1[e] = uw[(16+4*q+e)*32 + (r+16*mt)];
                }
                ua0 = cvt4(t0); ua1 = cvt4(t1);
            }
            #pragma unroll
            for (int nt=0; nt<4; nt++){
                f32x4 aU = MFMA16(ua0, xB[nt][0], z4);
                aU = MFMA16(ua1, xB[nt][1], aU);
                #pragma unroll
                for (int rg=0; rg<4; rg++) aU[rg] += ((const float*)&ubv4[mt])[rg];
                uB[nt][mt] = cvt4(aU);
            }
        }
    }

    bf16x4 hidB[4][4];
    #pragma unroll
    for (int mt=0; mt<4; mt++){
        bf16x4 ga = *(const bf16x4*)(G1a + (r+16*mt)*16 + 4*q);
        #pragma unroll
        for (int nt=0; nt<4; nt++){
            f32x4 acc = MFMA16(ga, kB[nt], z4);
            f32x4 g;
            #pragma unroll
            for (int i=0;i<4;i++) g[i]=gelu_f(acc[i]);
            hidB[mt][nt] = cvt4(g);
        }
    }

    f32x4 aF[2][4];
    {
        bf16x4 bb[4][2];
        #pragma unroll
        for (int nt=0; nt<4; nt++){
            int p = wv*64 + nt*16 + r;
            bb[nt][0] = *(const bf16x4*)(basis2P + p*32 + 4*q);
            bb[nt][1] = *(const bf16x4*)(basis2P + p*32 + 16 + 4*q);
        }
        #pragma unroll
        for (int mt=0; mt<2; mt++){
            bf16x4 t0 = *(const bf16x4*)(Tp + (size_t)bh*1024 + (r+16*mt)*32 + 4*q);
            bf16x4 t1 = *(const bf16x4*)(Tp + (size_t)bh*1024 + (r+16*mt)*32 + 16 + 4*q);
            #pragma unroll
            for (int nt=0; nt<4; nt++){
                f32x4 acc = MFMA16(t0, bb[nt][0], z4);
                aF[mt][nt] = MFMA16(t1, bb[nt][1], acc);
            }
        }
    }

    #pragma unroll
    for (int mt=0; mt<2; mt++){
        bf16x4 h0 = *(const bf16x4*)(HuT + (r+16*mt)*32 + 4*q);
        bf16x4 h1 = *(const bf16x4*)(HuT + (r+16*mt)*32 + 16 + 4*q);
        #pragma unroll
        for (int nt=0; nt<4; nt++){
            f32x4 aHu = MFMA16(h0, uB[nt][0], z4);
            aHu = MFMA16(h1, uB[nt][1], aHu);
            #pragma unroll
            for (int rg=0; rg<4; rg++)
                aF[mt][nt][rg] = (aHu[rg] + ((const float*)&hubv[mt])[rg]) - aF[mt][nt][rg];
        }
    }

    #pragma unroll
    for (int mt=0; mt<2; mt++){
        bf16x4 g2[4];
        #pragma unroll
        for (int ks=0; ks<4; ks++)
            g2[ks] = *(const bf16x4*)(G2T + (r+16*mt)*64 + 16*ks + 4*q);
        #pragma unroll
        for (int nt=0; nt<4; nt++){
            f32x4 aG = z4;
            #pragma unroll
            for (int ks=0; ks<4; ks++) aG = MFMA16(g2[ks], hidB[ks][nt], aG);
            #pragma unroll
            for (int rg=0; rg<4; rg++)
                aF[mt][nt][rg] = (aG[rg] + ((const float*)&gb2v[mt])[rg]) * aF[mt][nt][rg];
        }
    }

    bf16x4 bornB[2][4];
    #pragma unroll
    for (int mt=0; mt<2; mt++){
        bf16x4 w0 = *(const bf16x4*)(WuT + (r+16*mt)*32 + 4*q);
        bf16x4 w1 = *(const bf16x4*)(WuT + (r+16*mt)*32 + 16 + 4*q);
        #pragma unroll
        for (int nt=0; nt<4; nt++){
            f32x4 aW = MFMA16(w0, uB[nt][0], z4);
            aW = MFMA16(w1, uB[nt][1], aW);
            f32x4 brn;
            #pragma unroll
            for (int rg=0; rg<4; rg++)
                brn[rg] = (aW[rg] + ((const float*)&wubv[mt])[rg]) - aF[mt][nt][rg];
            bornB[mt][nt] = cvt4(brn);
        }
    }

    #pragma unroll
    for (int mt=0; mt<2; mt++){
        bf16x4 o0 = *(const bf16x4*)(owT + (r+16*mt)*32 + 4*q);
        bf16x4 o1 = *(const bf16x4*)(owT + (r+16*mt)*32 + 16 + 4*q);
        #pragma unroll
        for (int nt=0; nt<4; nt++){
            f32x4 aO = MFMA16(o0, bornB[0][nt], z4);
            aO = MFMA16(o1, bornB[1][nt], aO);
            float4 res;
            res.x = gelu_f(aO[0] + obv2[mt].x);
            res.y = gelu_f(aO[1] + obv2[mt].y);
            res.z = gelu_f(aO[2] + obv2[mt].z);
            res.w = gelu_f(aO[3] + obv2[mt].w);
            *(float4*)(out + ((size_t)bh*256 + wv*64 + nt*16 + r)*32 + 16*mt + 4*q) = res;
        }
    }
}

extern "C" void kernel_launch(void* const* d_in, const int* in_sizes, int n_in,
                              void* d_out, int out_size, void* d_ws, size_t ws_size,
                              hipStream_t stream)
{
    const float* x   = (const float*)d_in[0];
    const float* kk  = (const float*)d_in[1];
    const float* Lw1 = (const float*)d_in[2];
    const float* Lb1 = (const float*)d_in[3];
    const float* Lw2 = (const float*)d_in[4];
    const float* Lb2 = (const float*)d_in[5];
    const float* Gw1 = (const float*)d_in[6];
    const float* Gb1 = (const float*)d_in[7];
    const float* Gw2 = (const float*)d_in[8];
    const float* Gb2 = (const float*)d_in[9];
    const float* uw  = (const float*)d_in[10];
    const float* ub  = (const float*)d_in[11];
    const float* Wuw = (const float*)d_in[12];
    const float* Wub = (const float*)d_in[13];
    const float* Huw = (const float*)d_in[14];
    const float* Hub = (const float*)d_in[15];
    const float* Msw = (const float*)d_in[16];
    const float* Msb = (const float*)d_in[17];
    const float* ow  = (const float*)d_in[18];
    const float* ob  = (const float*)d_in[19];
    const float* k1r = (const float*)d_in[20];
    const float* k1i = (const float*)d_in[21];
    const float* k2r = (const float*)d_in[22];
    const float* k2i = (const float*)d_in[23];

    float* A1 = (float*)d_ws;                 // 1,572,864 floats (6 MB)
    short* Tp = (short*)(A1 + 1572864);       // 2,097,152 shorts (4 MB)
    short* tab = Tp + 2097152;
    short* G1a  = tab;               // 1024
    short* L1a  = G1a + 1024;        // 1024
    short* G2T  = L1a + 1024;        // 2048
    short* L2T  = G2T + 2048;        // 2048
    short* WuT  = L2T + 2048;        // 1024
    short* HuT  = WuT + 1024;        // 1024
    short* owT  = HuT + 1024;        // 1024
    short* uwT  = owT + 1024;        // 1024
    short* MsA  = uwT + 1024;        // 512
    short* basisW  = MsA + 512;      // 8192
    short* basis2P = basisW + 8192;  // 8192
    short* basisH1 = basis2P + 8192; // 12288
    short* basisH3 = basisH1 + 12288;// 16384
    short* Kp   = basisH3 + 16384;   // 589824
    short* SBg  = Kp + 589824;       // 393216
    short* uTg  = SBg + 393216;      // 16,777,216 shorts (33.5 MB)

    size_t need = (size_t)((char*)(uTg + 16777216) - (char*)d_ws);
    bool useU = ws_size >= need;

    float* outp = (float*)d_out;

    kern0<<<71, 256, 0, stream>>>(Lw1, Lb1, Lw2, Gw1, Gb1, Gw2, uw,
                                  Wuw, Huw, Msw, Msb, ow,
                                  k1r, k1i, k2r, k2i,
                                  G1a, L1a, G2T, L2T, WuT, HuT, owT, uwT, MsA,
                                  basisW, basis2P, basisH1, basisH3, Kp);
    if (useU){
        kernA<true><<<BB*128, 512, 0, stream>>>(x, kk, Lb2, ub, L1a, L2T, uwT, MsA, basisW, A1, uTg);
    } else {
        kernA<false><<<BB*128, 512, 0, stream>>>(x, kk, Lb2, ub, L1a, L2T, uwT, MsA, basisW, A1, uTg);
    }
    kernC1<<<BB*12, 512, 0, stream>>>(A1, basisH1, Kp, SBg);
    kernC2<<<BB*16, 256, 0, stream>>>(basisH3, SBg, Tp);
    if (useU){
        kernD<true><<<BB*128, 512, 0, stream>>>(x, kk, Gb2, ob, Wub, Hub, ub, uw,
                                                G1a, G2T, WuT, HuT, owT, basis2P, Tp, uTg, outp);
    } else {
        kernD<false><<<BB*128, 512, 0, stream>>>(x, kk, Gb2, ob, Wub, Hub, ub, uw,
                                                 G1a, G2T, WuT, HuT, owT, basis2P, Tp, uTg, outp);
    }
}

// Round 7
// 133.448 us; speedup vs baseline: 1.6091x; 1.1321x over previous
//
#include <hip/hip_runtime.h>
#include <math.h>

#define BB 8
#define NMODE 24

typedef __attribute__((ext_vector_type(8))) short bf16x8;
typedef __attribute__((ext_vector_type(4))) short bf16x4;
typedef __attribute__((ext_vector_type(4))) float f32x4;

#define MFMA32(a,b,c) __builtin_amdgcn_mfma_f32_16x16x32_bf16(a,b,c,0,0,0)

#if __has_builtin(__builtin_amdgcn_mfma_f32_16x16x16bf16_1k)
#define MFMA16(a,b,c) __builtin_amdgcn_mfma_f32_16x16x16bf16_1k(a,b,c,0,0,0)
#else
static __device__ __forceinline__ f32x4 MFMA16(bf16x4 a, bf16x4 b, f32x4 c){
    f32x4 d;
    asm("v_mfma_f32_16x16x16_bf16 %0, %1, %2, %3" : "=v"(d) : "v"(a), "v"(b), "v"(c));
    return d;
}
#endif

__device__ __forceinline__ short f2b(float f){
    unsigned u = __builtin_bit_cast(unsigned, f);
    u = (u + 0x7FFFu + ((u >> 16) & 1u)) >> 16;
    return (short)u;
}
__device__ __forceinline__ float b2f(short s){
    unsigned u = ((unsigned)(unsigned short)s) << 16;
    return __builtin_bit_cast(float, u);
}
__device__ __forceinline__ float gelu_f(float v) {
    float u = 0.7978845608028654f * (v + 0.044715f * v * v * v);
    float e = __expf(2.0f * u);
    float t = 1.0f - 2.0f / (e + 1.0f);
    return 0.5f * v * (1.0f + t);
}
__device__ __forceinline__ bf16x4 cvt4(f32x4 v){
    bf16x4 o;
    #pragma unroll
    for (int i=0;i<4;i++) o[i]=f2b(v[i]);
    return o;
}
__device__ __forceinline__ bf16x8 cvt8(float4 a, float4 b){
    bf16x8 o;
    o[0]=f2b(a.x); o[1]=f2b(a.y); o[2]=f2b(a.z); o[3]=f2b(a.w);
    o[4]=f2b(b.x); o[5]=f2b(b.y); o[6]=f2b(b.z); o[7]=f2b(b.w);
    return o;
}

// ======== kern0: precompute bf16 tables ========
__global__ __launch_bounds__(256) void kern0(
    const float* __restrict__ Lw1, const float* __restrict__ Lb1, const float* __restrict__ Lw2,
    const float* __restrict__ Gw1, const float* __restrict__ Gb1, const float* __restrict__ Gw2,
    const float* __restrict__ uw,
    const float* __restrict__ Wuw, const float* __restrict__ Huw,
    const float* __restrict__ Msw, const float* __restrict__ Msb,
    const float* __restrict__ ow,
    const float* __restrict__ k1r, const float* __restrict__ k1i,
    const float* __restrict__ k2r, const float* __restrict__ k2i,
    short* __restrict__ G1a, short* __restrict__ L1a,
    short* __restrict__ G2T, short* __restrict__ L2T,
    short* __restrict__ WuT, short* __restrict__ HuT,
    short* __restrict__ owT, short* __restrict__ uwT, short* __restrict__ MsA,
    short* __restrict__ basisW, short* __restrict__ basis2P,
    short* __restrict__ basisH1, short* __restrict__ basisH3,
    short* __restrict__ Kp)
{
    const int bid = blockIdx.x, t = threadIdx.x;
    const float tp = 6.28318530717958648f/256.f;
    if (bid == 0){
        for (int idx=t; idx<1024; idx+=256){
            int o = idx>>5, c = idx&31;
            WuT[o*32+c] = f2b(Wuw[c*32+o]);
        }
    } else if (bid == 1){
        for (int idx=t; idx<1024; idx+=256){
            int o = idx>>5, c = idx&31;
            HuT[o*32+c] = f2b(Huw[c*32+o]);
        }
    } else if (bid == 2){
        for (int idx=t; idx<1024; idx+=256){
            int hd = idx>>4, k2 = idx&15;
            G1a[idx] = f2b(k2<4 ? Gw1[k2*64+hd] : (k2==4 ? Gb1[hd] : 0.f));
            L1a[idx] = f2b(k2<4 ? Lw1[k2*64+hd] : (k2==4 ? Lb1[hd] : 0.f));
        }
    } else if (bid == 3){
        for (int idx=t; idx<2048; idx+=256){ int o=idx>>6, m=idx&63; G2T[idx]=f2b(Gw2[m*32+o]); }
    } else if (bid == 4){
        for (int idx=t; idx<2048; idx+=256){ int o=idx>>6, m=idx&63; L2T[idx]=f2b(Lw2[m*32+o]); }
    } else if (bid == 5){
        for (int idx=t; idx<1024; idx+=256){
            int o=idx>>5, c=idx&31;
            owT[idx]=f2b(ow[c*32+o]);
            uwT[idx]=f2b(uw[c*32+o]);
        }
    } else if (bid == 6){
        for (int idx=t; idx<512; idx+=256){
            int o=idx>>4, k2=idx&15;
            MsA[idx]=f2b(k2<4 ? Msw[k2*32+o] : (k2==4 ? Msb[o] : 0.f));
        }
    } else if (bid < 15){
        int base=(bid-7)*1024;
        for (int i=t; i<1024; i+=256){
            int idx=base+i; int m=idx>>8, w=idx&255;
            float v=0.f;
            if (m<12)       v = cosf(tp*(float)((m*w)&255));
            else if (m<24)  v = sinf(tp*(float)(((m-12)*w)&255));
            basisW[idx]=f2b(v);
        }
    } else if (bid < 23){
        int base=(bid-15)*1024;
        for (int i=t; i<1024; i+=256){
            int idx=base+i; int w=idx>>5, k=idx&31;
            float v=0.f;
            if (k<24){ int m=k>>1; float a=tp*(float)((m*w)&255); v=(k&1)? -sinf(a):cosf(a); }
            basis2P[idx]=f2b(v);
        }
    } else if (bid < 27){
        int base=(bid-23)*3072;
        for (int i=t; i<3072; i+=256){
            int idx=base+i; int m = idx>>8, h = idx&255;
            int mm = m % 24;
            int ia = (mm<12) ? mm : 232+mm;
            float a = tp*(float)((ia*h)&255);
            basisH1[idx] = f2b(m<24 ? cosf(a) : sinf(a));
        }
    } else if (bid < 35){
        int base=(bid-27)*2048;
        for (int i=t; i<2048; i+=256){
            int idx=base+i; int h = idx>>6, k = idx&63;
            float v = 0.f;
            if (k < 48){
                int mm = k % 24;
                int ia = (mm<12) ? mm : 232+mm;
                float a = tp*(float)((ia*h)&255);
                v = (k<24) ? cosf(a) : sinf(a);
            }
            basisH3[idx] = f2b(v);
        }
    } else {
        int base=(bid-35)*8192;
        for (int i=t; i<8192; i+=256){
            int pid = base + i;
            int o = pid & 31, c = (pid>>5) & 31;
            int rest = pid >> 10;
            int ii = rest % 24, jj = rest / 24;
            int iis = (ii<12) ? ii : ii-12;
            const float* wr = (ii<12) ? k1r : k2r;
            const float* wi = (ii<12) ? k1i : k2i;
            size_t widx = ((size_t)(c*32 + o)*12 + iis)*12 + jj;
            float sc = (jj==0 ? 1.f : 2.f) / 65536.f;
            Kp[2*pid]   = f2b(wr[widx] * sc);
            Kp[2*pid+1] = f2b(wi[widx] * sc);
        }
    }
}

// ======== kernA: 256 thr, 1 row/block, per-nt loop; v^T chain + w-DFT ========
__global__ __launch_bounds__(256, 3) void kernA(
    const float* __restrict__ x, const float* __restrict__ kk,
    const float* __restrict__ Lb2, const float* __restrict__ ubv,
    const short* __restrict__ L1a, const short* __restrict__ L2T,
    const short* __restrict__ uwT, const short* __restrict__ MsA,
    const short* __restrict__ basisW, float* __restrict__ A1)
{
    __shared__ short vT[32*264];   // [ch][pixel] padded
    const int bh = blockIdx.x, b = bh>>8, h = bh&255;
    const int tid = threadIdx.x, l = tid&63, wv = tid>>6;
    const int q = l>>4, r = l&15;
    const f32x4 z4 = {0.f,0.f,0.f,0.f};

    // persistent weight fragments
    bf16x4 la[4], ma[2], l2f[2][4];
    bf16x8 ua8[2];
    #pragma unroll
    for (int mt=0; mt<4; mt++) la[mt] = *(const bf16x4*)(L1a + (r+16*mt)*16 + 4*q);
    #pragma unroll
    for (int mt=0; mt<2; mt++){
        ma[mt]  = *(const bf16x4*)(MsA + (r+16*mt)*16 + 4*q);
        ua8[mt] = *(const bf16x8*)(uwT + (r+16*mt)*32 + 8*q);
        #pragma unroll
        for (int ks=0; ks<4; ks++)
            l2f[mt][ks] = *(const bf16x4*)(L2T + (r+16*mt)*64 + 16*ks + 4*q);
    }
    f32x4 lb2v[2], ubv4[2];
    #pragma unroll
    for (int mt=0; mt<2; mt++){
        lb2v[mt] = *(const f32x4*)(Lb2 + 16*mt + 4*q);
        ubv4[mt] = *(const f32x4*)(ubv + 16*mt + 4*q);
    }

    #pragma unroll
    for (int nt=0; nt<4; nt++){
        const int p = wv*64 + nt*16 + r;
        // x as MFMA32 B-frag (k = 8q+e)
        const float* xp = x + ((size_t)bh*256 + p)*32 + 8*q;
        float4 x0 = *(const float4*)xp;
        float4 x1 = *(const float4*)(xp + 4);
        bf16x8 xB8 = cvt8(x0, x1);
        // k bias-augmented MFMA16 B-frag (k = 4q+e)
        bf16x4 kB = {0,0,0,0};
        if (q==0){
            float4 k4 = *(const float4*)(kk + ((size_t)bh*256 + p)*4);
            kB[0]=f2b(k4.x); kB[1]=f2b(k4.y); kB[2]=f2b(k4.z); kB[3]=f2b(k4.w);
        } else if (q==1){ kB[0] = (short)0x3F80; }

        // hidden(L) = gelu(k@Lw1 + Lb1)
        bf16x4 hidL[4];
        #pragma unroll
        for (int mt=0; mt<4; mt++){
            f32x4 acc = MFMA16(la[mt], kB, z4);
            f32x4 g;
            #pragma unroll
            for (int i=0;i<4;i++) g[i]=gelu_f(acc[i]);
            hidL[mt] = cvt4(g);
        }
        #pragma unroll
        for (int mt=0; mt<2; mt++){
            f32x4 aU = MFMA32(ua8[mt], xB8, ubv4[mt]);   // u incl bias
            f32x4 aM = MFMA16(ma[mt], kB, z4);           // Ms incl bias (aug)
            f32x4 aL = lb2v[mt];                          // L incl bias
            #pragma unroll
            for (int ks=0; ks<4; ks++) aL = MFMA16(l2f[mt][ks], hidL[ks], aL);
            #pragma unroll
            for (int rg=0; rg<4; rg++){
                int ch = 16*mt + 4*q + rg;
                vT[ch*264 + p] = f2b(aL[rg] * aU[rg] + aM[rg]);
            }
        }
    }
    __syncthreads();

    // w-DFT: C[mode][ch] = sum_w basisW[mode][w] * v^T[ch][w]
    const int mt2 = wv>>1, nt2 = wv&1;
    f32x4 accD = z4;
    #pragma unroll
    for (int ks=0; ks<8; ks++){
        bf16x8 av = *(const bf16x8*)(basisW + (r+16*mt2)*256 + 32*ks + 8*q);
        bf16x8 bv = *(const bf16x8*)(&vT[(r+16*nt2)*264 + 32*ks + 8*q]);
        accD = MFMA32(av, bv, accD);
    }
    #pragma unroll
    for (int rg=0; rg<4; rg++){
        int mode = 16*mt2 + 4*q + rg;
        int ch = r + 16*nt2;
        if (mode < 12)
            A1[((size_t)(b*12+mode)*256 + h)*64 + ch*2] = accD[rg];
        else if (mode < 24)
            A1[((size_t)(b*12+mode-12)*256 + h)*64 + ch*2 + 1] = -accD[rg];
    }
}

// ======== kernC1: per (b,j): MFMA h-DFT + spectral multiply -> SBg ========
__global__ __launch_bounds__(512) void kernC1(
    const float* __restrict__ A1, const short* __restrict__ basisH1,
    const short* __restrict__ Kp, short* __restrict__ SBg)
{
    __shared__ float C1L[48*66];
    const int bj = blockIdx.x;
    const int j  = bj % 12;
    const int tid = threadIdx.x, l = tid&63, w = tid>>6;
    const int q = l>>4, r = l&15;
    const f32x4 z4 = {0.f,0.f,0.f,0.f};

    {
        const float* Ag = A1 + (size_t)bj*16384;
        const int nt  = w & 3;
        const int nmt = (w < 4) ? 2 : 1;
        const int mt0 = (w < 4) ? 0 : 2;
        f32x4 acc[2] = {z4, z4};
        for (int ks=0; ks<8; ks++){
            bf16x8 bv;
            #pragma unroll
            for (int e=0;e<8;e++)
                bv[e] = f2b(Ag[(ks*32 + q*8 + e)*64 + nt*16 + r]);
            #pragma unroll
            for (int mi=0; mi<2; mi++){
                if (mi < nmt){
                    bf16x8 av = *(const bf16x8*)(basisH1 + (r + 16*(mt0+mi))*256 + ks*32 + q*8);
                    acc[mi] = MFMA32(av, bv, acc[mi]);
                }
            }
        }
        #pragma unroll
        for (int mi=0; mi<2; mi++){
            if (mi < nmt){
                #pragma unroll
                for (int rg=0; rg<4; rg++)
                    C1L[(16*(mt0+mi) + 4*q + rg)*66 + 16*nt + r] = acc[mi][rg];
            }
        }
    }
    __syncthreads();

    {
        const int o = tid & 31, g = tid >> 5;
        short* SB = SBg + (size_t)bj*4096;
        #pragma unroll
        for (int half=0; half<2; half++){
            int i = g + 16*half;
            if (i < 24){
                float Sre=0.f, Sim=0.f;
                const short* kp = Kp + ((size_t)(j*24 + i)*32)*64 + 2*o;
                #pragma unroll 4
                for (int c=0; c<32; c++){
                    float vr = C1L[i*66 + 2*c]     + C1L[(24+i)*66 + 2*c+1];
                    float vi = C1L[i*66 + 2*c + 1] - C1L[(24+i)*66 + 2*c];
                    short2 kv = *(const short2*)(kp + c*64);
                    float kr = b2f(kv.x), ki = b2f(kv.y);
                    Sre += vr*kr - vi*ki;
                    Sim += vr*ki + vi*kr;
                }
                SB[o*64 + i]           = f2b(Sre);
                SB[o*64 + 24 + i]      = f2b(-Sim);
                SB[2048 + o*64 + i]    = f2b(Sim);
                SB[2048 + o*64 + 24+i] = f2b(Sre);
            }
        }
        int o2 = (tid >> 4) & 31, kz = 48 + (tid & 15);
        SB[o2*64 + kz] = 0;
        SB[2048 + o2*64 + kz] = 0;
    }
}

// ======== kernC2: per (b, htile): inverse h-DFT for ALL j, dense Tp dump ========
__global__ __launch_bounds__(256) void kernC2(
    const short* __restrict__ basisH3, const short* __restrict__ SBg,
    short* __restrict__ Tp)
{
    __shared__ __align__(16) short Tt[16*1024];
    const int bid = blockIdx.x;
    const int b = bid >> 4, ht = bid & 15;
    const int tid = threadIdx.x, l = tid&63, w = tid>>6;
    const int q = l>>4, r = l&15;
    const f32x4 z4 = {0.f,0.f,0.f,0.f};

    for (int idx = tid; idx < 512; idx += 256){
        int hh = idx >> 5, o = idx & 31;
        #pragma unroll
        for (int kkz=0; kkz<8; kkz++) Tt[(hh*32+o)*32 + 24 + kkz] = 0;
    }

    bf16x8 af[2];
    #pragma unroll
    for (int ks=0; ks<2; ks++)
        af[ks] = *(const bf16x8*)(basisH3 + (ht*16 + r)*64 + ks*32 + q*8);

    #pragma unroll
    for (int jj=0; jj<3; jj++){
        int j = w*3 + jj;
        const short* SB = SBg + (size_t)(b*12 + j)*4096;
        #pragma unroll
        for (int nt=0; nt<2; nt++){
            f32x4 aRe = z4, aIm = z4;
            #pragma unroll
            for (int ks=0; ks<2; ks++){
                bf16x8 b1 = *(const bf16x8*)(SB + (16*nt + r)*64 + ks*32 + q*8);
                bf16x8 b2 = *(const bf16x8*)(SB + 2048 + (16*nt + r)*64 + ks*32 + q*8);
                aRe = MFMA32(af[ks], b1, aRe);
                aIm = MFMA32(af[ks], b2, aIm);
            }
            #pragma unroll
            for (int rg=0; rg<4; rg++){
                int hl = 4*q + rg, o = 16*nt + r;
                *(short2*)&Tt[(hl*32 + o)*32 + 2*j] = make_short2(f2b(aRe[rg]), f2b(aIm[rg]));
            }
        }
    }
    __syncthreads();

    short* dst = Tp + (size_t)(b*256 + ht*16)*1024;
    #pragma unroll
    for (int it=0; it<8; it++){
        int off = (tid + it*256)*8;
        *(int4*)(dst + off) = *(const int4*)&Tt[off];
    }
}

// ======== kernD: 256 thr, 1 row/block, per-nt loop, in-register chain ========
__global__ __launch_bounds__(256, 3) void kernD(
    const float* __restrict__ x, const float* __restrict__ kk,
    const float* __restrict__ Gb2, const float* __restrict__ obv,
    const float* __restrict__ Wub, const float* __restrict__ Hub,
    const float* __restrict__ ubv,
    const short* __restrict__ G1a, const short* __restrict__ G2T,
    const short* __restrict__ uwT,
    const short* __restrict__ WuT, const short* __restrict__ HuT,
    const short* __restrict__ owT, const short* __restrict__ basis2P,
    const short* __restrict__ Tp, float* __restrict__ out)
{
    const int bh = blockIdx.x;
    const int tid = threadIdx.x, l = tid&63, wv = tid>>6;
    const int q = l>>4, r = l&15;
    const f32x4 z4 = {0.f,0.f,0.f,0.f};

    // persistent weight fragments
    bf16x4 ga[4], g2f[2][4], wuf[2][2], huf[2][2], owf[2][2];
    bf16x8 ua8[2], tp8[2];
    #pragma unroll
    for (int mt=0; mt<4; mt++) ga[mt] = *(const bf16x4*)(G1a + (r+16*mt)*16 + 4*q);
    #pragma unroll
    for (int mt=0; mt<2; mt++){
        ua8[mt] = *(const bf16x8*)(uwT + (r+16*mt)*32 + 8*q);
        tp8[mt] = *(const bf16x8*)(Tp + (size_t)bh*1024 + (r+16*mt)*32 + 8*q);
        #pragma unroll
        for (int ks=0; ks<4; ks++)
            g2f[mt][ks] = *(const bf16x4*)(G2T + (r+16*mt)*64 + 16*ks + 4*q);
        #pragma unroll
        for (int ks=0; ks<2; ks++){
            wuf[mt][ks] = *(const bf16x4*)(WuT + (r+16*mt)*32 + 16*ks + 4*q);
            huf[mt][ks] = *(const bf16x4*)(HuT + (r+16*mt)*32 + 16*ks + 4*q);
            owf[mt][ks] = *(const bf16x4*)(owT + (r+16*mt)*32 + 16*ks + 4*q);
        }
    }
    f32x4 gb2v[2], obv2[2], wubv[2], hubv[2], ubv4[2];
    #pragma unroll
    for (int mt=0; mt<2; mt++){
        gb2v[mt] = *(const f32x4*)(Gb2 + 16*mt + 4*q);
        obv2[mt] = *(const f32x4*)(obv + 16*mt + 4*q);
        wubv[mt] = *(const f32x4*)(Wub + 16*mt + 4*q);
        hubv[mt] = *(const f32x4*)(Hub + 16*mt + 4*q);
        ubv4[mt] = *(const f32x4*)(ubv + 16*mt + 4*q);
    }

    #pragma unroll
    for (int nt=0; nt<4; nt++){
        const int p = wv*64 + nt*16 + r;
        // loads
        const float* xp = x + ((size_t)bh*256 + p)*32 + 8*q;
        float4 x0 = *(const float4*)xp;
        float4 x1 = *(const float4*)(xp + 4);
        bf16x8 xB8 = cvt8(x0, x1);
        bf16x4 kB = {0,0,0,0};
        if (q==0){
            float4 k4 = *(const float4*)(kk + ((size_t)bh*256 + p)*4);
            kB[0]=f2b(k4.x); kB[1]=f2b(k4.y); kB[2]=f2b(k4.z); kB[3]=f2b(k4.w);
        } else if (q==1){ kB[0] = (short)0x3F80; }
        bf16x8 bb8 = *(const bf16x8*)(basis2P + p*32 + 8*q);

        // u = x@uw + ub (one MFMA32 per mt), repack C->B frag
        bf16x4 uB[2];
        #pragma unroll
        for (int mt=0; mt<2; mt++)
            uB[mt] = cvt4(MFMA32(ua8[mt], xB8, ubv4[mt]));

        // hidden(G) = gelu(k@Gw1 + Gb1)
        bf16x4 hidG[4];
        #pragma unroll
        for (int mt=0; mt<4; mt++){
            f32x4 acc = MFMA16(ga[mt], kB, z4);
            f32x4 g;
            #pragma unroll
            for (int i=0;i<4;i++) g[i]=gelu_f(acc[i]);
            hidG[mt] = cvt4(g);
        }

        // born = (Wu) - (G)*( (Hu) - Fv )
        bf16x4 bornB[2];
        #pragma unroll
        for (int mt=0; mt<2; mt++){
            f32x4 aFv = MFMA32(tp8[mt], bb8, z4);
            f32x4 aHu = hubv[mt];
            f32x4 aW  = wubv[mt];
            #pragma unroll
            for (int ks=0; ks<2; ks++){
                aHu = MFMA16(huf[mt][ks], uB[ks], aHu);
                aW  = MFMA16(wuf[mt][ks], uB[ks], aW);
            }
            f32x4 aG = gb2v[mt];
            #pragma unroll
            for (int ks=0; ks<4; ks++) aG = MFMA16(g2f[mt][ks], hidG[ks], aG);
            f32x4 brn;
            #pragma unroll
            for (int rg=0; rg<4; rg++)
                brn[rg] = aW[rg] - aG[rg] * (aHu[rg] - aFv[rg]);
            bornB[mt] = cvt4(brn);
        }

        // out = gelu(born @ ow + ob)
        #pragma unroll
        for (int mt=0; mt<2; mt++){
            f32x4 aO = obv2[mt];
            #pragma unroll
            for (int ks=0; ks<2; ks++) aO = MFMA16(owf[mt][ks], bornB[ks], aO);
            float4 res;
            res.x = gelu_f(aO[0]);
            res.y = gelu_f(aO[1]);
            res.z = gelu_f(aO[2]);
            res.w = gelu_f(aO[3]);
            *(float4*)(out + ((size_t)bh*256 + p)*32 + 16*mt + 4*q) = res;
        }
    }
}

extern "C" void kernel_launch(void* const* d_in, const int* in_sizes, int n_in,
                              void* d_out, int out_size, void* d_ws, size_t ws_size,
                              hipStream_t stream)
{
    const float* x   = (const float*)d_in[0];
    const float* kk  = (const float*)d_in[1];
    const float* Lw1 = (const float*)d_in[2];
    const float* Lb1 = (const float*)d_in[3];
    const float* Lw2 = (const float*)d_in[4];
    const float* Lb2 = (const float*)d_in[5];
    const float* Gw1 = (const float*)d_in[6];
    const float* Gb1 = (const float*)d_in[7];
    const float* Gw2 = (const float*)d_in[8];
    const float* Gb2 = (const float*)d_in[9];
    const float* uw  = (const float*)d_in[10];
    const float* ub  = (const float*)d_in[11];
    const float* Wuw = (const float*)d_in[12];
    const float* Wub = (const float*)d_in[13];
    const float* Huw = (const float*)d_in[14];
    const float* Hub = (const float*)d_in[15];
    const float* Msw = (const float*)d_in[16];
    const float* Msb = (const float*)d_in[17];
    const float* ow  = (const float*)d_in[18];
    const float* ob  = (const float*)d_in[19];
    const float* k1r = (const float*)d_in[20];
    const float* k1i = (const float*)d_in[21];
    const float* k2r = (const float*)d_in[22];
    const float* k2i = (const float*)d_in[23];

    float* A1 = (float*)d_ws;                 // 1,572,864 floats (6 MB)
    short* Tp = (short*)(A1 + 1572864);       // 2,097,152 shorts (4 MB)
    short* tab = Tp + 2097152;
    short* G1a  = tab;               // 1024
    short* L1a  = G1a + 1024;        // 1024
    short* G2T  = L1a + 1024;        // 2048
    short* L2T  = G2T + 2048;        // 2048
    short* WuT  = L2T + 2048;        // 1024
    short* HuT  = WuT + 1024;        // 1024
    short* owT  = HuT + 1024;        // 1024
    short* uwT  = owT + 1024;        // 1024
    short* MsA  = uwT + 1024;        // 512
    short* basisW  = MsA + 512;      // 8192
    short* basis2P = basisW + 8192;  // 8192
    short* basisH1 = basis2P + 8192; // 12288
    short* basisH3 = basisH1 + 12288;// 16384
    short* Kp   = basisH3 + 16384;   // 589824
    short* SBg  = Kp + 589824;       // 393216

    float* outp = (float*)d_out;

    kern0<<<71, 256, 0, stream>>>(Lw1, Lb1, Lw2, Gw1, Gb1, Gw2, uw,
                                  Wuw, Huw, Msw, Msb, ow,
                                  k1r, k1i, k2r, k2i,
                                  G1a, L1a, G2T, L2T, WuT, HuT, owT, uwT, MsA,
                                  basisW, basis2P, basisH1, basisH3, Kp);
    kernA<<<BB*256, 256, 0, stream>>>(x, kk, Lb2, ub, L1a, L2T, uwT, MsA, basisW, A1);
    kernC1<<<BB*12, 512, 0, stream>>>(A1, basisH1, Kp, SBg);
    kernC2<<<BB*16, 256, 0, stream>>>(basisH3, SBg, Tp);
    kernD<<<BB*256, 256, 0, stream>>>(x, kk, Gb2, ob, Wub, Hub, ub,
                                      G1a, G2T, uwT, WuT, HuT, owT,
                                      basis2P, Tp, outp);
}